// Round 11
// baseline (2204.541 us; speedup 1.0000x reference)
//
#include <hip/hip_runtime.h>
#include <math.h>

#define T_LEN 8000
#define BATCH 2
#define CCH 512
#define SKP 256
#define AUXP 32
#define NQ 256
#define NLAYER 30
#define PADF 512
#define TPAD 8192
#define ROWS (PADF + TPAD)         // 8704 padded rows
#define HROWS TPAD                 // 8192 rows (z, h, y1)

typedef unsigned short hfu;        // fp16 as raw bits
typedef unsigned int u32;
typedef __attribute__((ext_vector_type(8))) _Float16 half8;
typedef __attribute__((ext_vector_type(4))) float f32x4;

#define GLOAD16(g, l)                                                          \
  __builtin_amdgcn_global_load_lds(                                            \
      (const __attribute__((address_space(1))) void*)(g),                      \
      (__attribute__((address_space(3))) void*)(l), 16, 0, 0)

__device__ inline hfu hfbits(float f) {
  union { _Float16 h; hfu u; } x;
  x.h = (_Float16)f;
  return x.u;
}
__device__ inline u32 pk2(float a, float b) {
  return (u32)hfbits(a) | ((u32)hfbits(b) << 16);
}
__device__ inline uint4 pk8(const float f[8]) {
  return make_uint4(pk2(f[0], f[1]), pk2(f[2], f[3]), pk2(f[4], f[5]), pk2(f[6], f[7]));
}
// pair-interleaved XOR LDS layout for BK=32 tiles (4 chunks of 16B per row).
// Staging inverse: slot s -> pr=s>>3, w=s&7, row=2*pr+(w&1), ck=(w>>1)^(pr&3).
__device__ inline int ldsL(int row, int ck) {
  return ((row >> 1) << 3) + ((((ck) ^ ((row >> 1) & 3)) << 1) | (row & 1));
}

// ---------------- utility: zero / converts ----------------
__global__ __launch_bounds__(256) void zero16(uint4* p, int n) {
  for (int i = blockIdx.x * 256 + threadIdx.x; i < n; i += gridDim.x * 256)
    p[i] = make_uint4(0u, 0u, 0u, 0u);
}

// dil weights: in [30][512][512][2] f32 -> out [30][2][512][512] fp16 (tap-deinterleaved)
__global__ __launch_bounds__(256) void cvt_dil(const float* __restrict__ in, hfu* __restrict__ out) {
  const long NG = (long)NLAYER * CCH * (CCH / 4);
  for (long g = (long)blockIdx.x * 256 + threadIdx.x; g < NG; g += (long)gridDim.x * 256) {
    const int i4 = (int)(g & 127) * 4;
    const int o = (int)((g >> 7) & 511);
    const int l = (int)(g >> 16);
    const float* pp = in + (((size_t)l * CCH + o) * CCH + i4) * 2;
    float4 f0 = *(const float4*)pp;
    float4 f1 = *(const float4*)(pp + 4);
    uint2 t0 = make_uint2(pk2(f0.x, f0.z), pk2(f1.x, f1.z));
    uint2 t1 = make_uint2(pk2(f0.y, f0.w), pk2(f1.y, f1.w));
    hfu* ob = out + ((size_t)l * 2 * CCH + o) * CCH + i4;
    *(uint2*)ob = t0;
    *(uint2*)(ob + (size_t)CCH * CCH) = t1;
  }
}

// skip_w [30][256][512] + res_w [30][512][512] -> stacked [30][768][512] fp16
__global__ __launch_bounds__(256) void cvt_skipres(const float* __restrict__ skw,
                                                   const float* __restrict__ rsw,
                                                   hfu* __restrict__ out) {
  const long NG = (long)NLAYER * 768 * (CCH / 4);
  for (long g = (long)blockIdx.x * 256 + threadIdx.x; g < NG; g += (long)gridDim.x * 256) {
    const int i4 = (int)(g & 127) * 4;
    const int r = (int)((g >> 7) % 768);
    const int l = (int)(g / (128 * 768));
    const float* src = (r < SKP) ? (skw + ((size_t)l * SKP + r) * CCH + i4)
                                 : (rsw + ((size_t)l * CCH + (r - SKP)) * CCH + i4);
    float4 f = *(const float4*)src;
    *(uint2*)(out + ((size_t)l * 768 + r) * CCH + i4) = make_uint2(pk2(f.x, f.y), pk2(f.z, f.w));
  }
}

// aux weights [30][512][28] -> [30][512][32] fp16 zero-padded
__global__ __launch_bounds__(256) void cvt_aux(const float* __restrict__ in, hfu* __restrict__ out) {
  const int N = NLAYER * CCH * AUXP;
  for (int i = blockIdx.x * 256 + threadIdx.x; i < N; i += gridDim.x * 256) {
    const int j = i & 31;
    const int o = (i >> 5) & 511;
    const int l = i >> 14;
    float v = (j < 28) ? in[((size_t)l * CCH + o) * 28 + j] : 0.f;
    out[i] = hfbits(v);
  }
}

__global__ __launch_bounds__(256) void cvt_copy(const float* __restrict__ in, hfu* __restrict__ out, int n) {
  for (int i = blockIdx.x * 256 + threadIdx.x; i < n; i += gridDim.x * 256)
    out[i] = hfbits(in[i]);
}

// causal_w [512][256][2] f32 -> cwt [2][256][512] f32 (transposed for coalesced embed)
__global__ __launch_bounds__(256) void cvt_cwt(const float* __restrict__ cw, float* __restrict__ out) {
  const int N = 2 * NQ * CCH;
  for (int i = blockIdx.x * 256 + threadIdx.x; i < N; i += gridDim.x * 256) {
    const int tap = i >> 17;
    const int r = i & 131071;
    const int xq = r >> 9;
    const int o = r & 511;
    out[i] = cw[((size_t)o * NQ + xq) * 2 + tap];
  }
}

// h [b][28][8000] f32 -> [b][8192][32] fp16 zero-padded
__global__ __launch_bounds__(256) void htrans_kernel(const float* __restrict__ h, hfu* __restrict__ hbf) {
  const int b = blockIdx.y;
  const int t = blockIdx.x * 64 + (threadIdx.x & 63);
  const int j0 = threadIdx.x >> 6;
#pragma unroll
  for (int j = j0; j < AUXP; j += 4) {
    float v = (j < 28 && t < T_LEN) ? h[((size_t)b * 28 + j) * T_LEN + t] : 0.f;
    hbf[((size_t)b * HROWS + t) * AUXP + j] = hfbits(v);
  }
}

// ---------------- embed (coalesced via cwt) ----------------
template <int PRE>
__global__ __launch_bounds__(256) void embed_kernel(const int* __restrict__ x,
                                                    const float* __restrict__ cwt,
                                                    const float* __restrict__ cb,
                                                    float* __restrict__ outf,
                                                    hfu* __restrict__ outb) {
  const int b = blockIdx.y;
  const int t = blockIdx.x * 4 + (threadIdx.x >> 6);
  const int o = (threadIdx.x & 63) * 8;
  const int xc = x[(size_t)b * T_LEN + t] & 255;
  const int xp = (t > 0) ? (x[(size_t)b * T_LEN + t - 1] & 255) : 0;
  const float won = (t > 0) ? 1.f : 0.f;
  const float* c1 = cwt + 131072 + (size_t)xc * CCH + o;
  const float* c0 = cwt + (size_t)xp * CCH + o;
  float v[8];
#pragma unroll
  for (int j = 0; j < 8; ++j) v[j] = cb[o + j] + c1[j] + won * c0[j];
  if (PRE) {
    *(uint4*)&outb[((size_t)b * ROWS + PADF + t) * CCH + o] = pk8(v);
  } else {
    float* po = outf + ((size_t)b * ROWS + PADF + t) * CCH + o;
    *(float4*)po = make_float4(v[0], v[1], v[2], v[3]);
    *(float4*)(po + 4) = make_float4(v[4], v[5], v[6], v[7]);
  }
}

// ---------------- gate: sig/tanh dilated GEMMs + aux + gating ----------------
// BM=64, BN=256, BK=32, 512 threads (8 waves: wm2 x wn4, mr2 x nr4).
// Grid 512 = 2 blocks/CU (8 XCD x 64; xcd owns t in [xcd*1024,(xcd+1)*1024)).
// 3-phase LDS ring (72KB), ONE barrier per K-step, depth-2 vmcnt(3).
template <int PRE>
__global__ __launch_bounds__(512, 4) void gate_kernel(
    const hfu* __restrict__ actb, const float* __restrict__ actf,
    const hfu* __restrict__ hbf,
    const void* __restrict__ wsp, const void* __restrict__ wtp,
    const hfu* __restrict__ auxs, const hfu* __restrict__ auxt,
    const float* __restrict__ bs1, const float* __restrict__ bs2,
    const float* __restrict__ bt1, const float* __restrict__ bt2,
    hfu* __restrict__ z, int d) {
  // 72KB: 3 phases x {As 256, At 256, B 1024} uint4
  __shared__ uint4 sm[4608];
  const int tid = threadIdx.x;
  const int lane = tid & 63, wid = tid >> 6;
  const int wm = wid >> 2, wn = wid & 3;
  const int lr = lane & 15, lq = lane >> 4;

  const int n = blockIdx.x;               // 512 = 8 xcd * 64
  const int f = (n & 7) * 64 + (n >> 3);
  const int tt = f >> 4, inner = f & 15;  // 32 t-tiles x (8 og x 2 b)
  const int o0 = (inner >> 1) * 64;
  const int b = inner & 1;
  const int t0 = tt * 256;

  f32x4 accS[2][4] = {};
  f32x4 accT[2][4] = {};

  // stage step ih (0..31 dil, 32 = aux): exactly 3 loads/thread.
  // waves 0-3 stage As (sig), waves 4-7 stage At (tanh); all stage B.
  auto stage = [&](int ih, int p) {
    const int base = p * 1536;
    const int s = tid & 255;
    const int pr = s >> 3, w = s & 7;
    const int row = (pr << 1) | (w & 1);        // 0..63
    const int ck = (w >> 1) ^ (pr & 3);         // 0..3
    if (ih < 32) {
      const int tau = (ih < 16) ? 1 : 0;
      const int koff = (ih & 15) * 32;
      if (PRE) {
        const hfu* wsel = (tid < 256) ? (const hfu*)wsp : (const hfu*)wtp;
        GLOAD16(wsel + ((size_t)tau * CCH + o0 + row) * CCH + koff + ck * 8, &sm[base + tid]);
#pragma unroll
        for (int c = 0; c < 2; ++c) {
          const int s2 = c * 512 + tid;
          const int pr2 = s2 >> 3, w2 = s2 & 7;
          const int row2 = (pr2 << 1) | (w2 & 1);  // 0..255
          const int ck2 = (w2 >> 1) ^ (pr2 & 3);
          const hfu* ar = actb + ((size_t)b * ROWS + PADF + t0 + row2 - (tau ? 0 : d)) * CCH + koff + ck2 * 8;
          GLOAD16(ar, &sm[base + 512 + s2]);
        }
      } else {
        const float* wsel = (tid < 256) ? (const float*)wsp : (const float*)wtp;
        const size_t fb = ((size_t)(o0 + row) * CCH + koff + ck * 8) * 2;
        float vs[8];
#pragma unroll
        for (int j = 0; j < 4; ++j) {
          float4 fs = *(const float4*)&wsel[fb + j * 4];
          vs[2 * j] = tau ? fs.y : fs.x;
          vs[2 * j + 1] = tau ? fs.w : fs.z;
        }
        sm[base + tid] = pk8(vs);
#pragma unroll
        for (int c = 0; c < 2; ++c) {
          const int s2 = c * 512 + tid;
          const int pr2 = s2 >> 3, w2 = s2 & 7;
          const int row2 = (pr2 << 1) | (w2 & 1);
          const int ck2 = (w2 >> 1) ^ (pr2 & 3);
          const float* ar = actf + ((size_t)b * ROWS + PADF + t0 + row2 - (tau ? 0 : d)) * CCH + koff + ck2 * 8;
          float4 f0 = *(const float4*)&ar[0];
          float4 f1 = *(const float4*)&ar[4];
          float vb[8] = {f0.x, f0.y, f0.z, f0.w, f1.x, f1.y, f1.z, f1.w};
          sm[base + 512 + s2] = pk8(vb);
        }
      }
    } else {
      // aux step: identical K=32 geometry (AUXP=32)
      const hfu* asel = (tid < 256) ? auxs : auxt;
      if (PRE) {
        GLOAD16(asel + (size_t)(o0 + row) * AUXP + ck * 8, &sm[base + tid]);
      } else {
        sm[base + tid] = *(const uint4*)&asel[(size_t)(o0 + row) * AUXP + ck * 8];
      }
#pragma unroll
      for (int c = 0; c < 2; ++c) {
        const int s2 = c * 512 + tid;
        const int pr2 = s2 >> 3, w2 = s2 & 7;
        const int row2 = (pr2 << 1) | (w2 & 1);
        const int ck2 = (w2 >> 1) ^ (pr2 & 3);
        if (PRE)
          GLOAD16(hbf + ((size_t)b * HROWS + t0 + row2) * AUXP + ck2 * 8, &sm[base + 512 + s2]);
        else
          sm[base + 512 + s2] = *(const uint4*)&hbf[((size_t)b * HROWS + t0 + row2) * AUXP + ck2 * 8];
      }
    }
  };

  // one K=32 step: 8 ds_read_b128, 16 MFMAs per wave
  auto compute = [&](int p) {
    const int base = p * 1536;
    half8 af[2], ag[2], bv[4];
#pragma unroll
    for (int mr = 0; mr < 2; ++mr) {
      const int row = wm * 32 + mr * 16 + lr;
      const int idx = ldsL(row, lq);
      af[mr] = *(const half8*)&sm[base + idx];
      ag[mr] = *(const half8*)&sm[base + 256 + idx];
    }
#pragma unroll
    for (int nr = 0; nr < 4; ++nr) {
      const int row = wn * 64 + nr * 16 + lr;
      bv[nr] = *(const half8*)&sm[base + 512 + ldsL(row, lq)];
    }
#pragma unroll
    for (int mr = 0; mr < 2; ++mr)
#pragma unroll
      for (int nr = 0; nr < 4; ++nr) {
        accS[mr][nr] = __builtin_amdgcn_mfma_f32_16x16x32_f16(af[mr], bv[nr], accS[mr][nr], 0, 0, 0);
        accT[mr][nr] = __builtin_amdgcn_mfma_f32_16x16x32_f16(ag[mr], bv[nr], accT[mr][nr], 0, 0, 0);
      }
  };

  if (PRE) {
    stage(0, 0);
    stage(1, 1);
    for (int ih = 0; ih < 33; ++ih) {
      if (ih < 32)
        asm volatile("s_waitcnt vmcnt(3)" ::: "memory");  // step-ih landed; next 3 fly
      else
        asm volatile("s_waitcnt vmcnt(0)" ::: "memory");
      __builtin_amdgcn_s_barrier();                        // ONE barrier per step
      __builtin_amdgcn_sched_barrier(0);
      if (ih < 31) stage(ih + 2, (ih + 2) % 3);            // overwrites phase read at ih-1
      __builtin_amdgcn_s_setprio(1);
      compute(ih % 3);
      __builtin_amdgcn_s_setprio(0);
      __builtin_amdgcn_sched_barrier(0);
    }
  } else {
    for (int ih = 0; ih < 33; ++ih) {
      stage(ih, ih % 3);
      __syncthreads();
      compute(ih % 3);
      __syncthreads();
    }
  }

  // epilogue: bias + sigmoid*tanh -> z fp16 [b][t][ch]
#pragma unroll
  for (int mr = 0; mr < 2; ++mr) {
    const int ob = o0 + wm * 32 + mr * 16 + lq * 4;
    float4 x1 = *(const float4*)&bs1[ob];
    float4 x2 = *(const float4*)&bs2[ob];
    float4 y1 = *(const float4*)&bt1[ob];
    float4 y2 = *(const float4*)&bt2[ob];
    const float sb[4] = {x1.x + x2.x, x1.y + x2.y, x1.z + x2.z, x1.w + x2.w};
    const float tb[4] = {y1.x + y2.x, y1.y + y2.y, y1.z + y2.z, y1.w + y2.w};
#pragma unroll
    for (int nr = 0; nr < 4; ++nr) {
      const int t = t0 + wn * 64 + nr * 16 + lr;
      float zv[4];
#pragma unroll
      for (int j = 0; j < 4; ++j) {
        float sv = accS[mr][nr][j] + sb[j];
        float tv = accT[mr][nr][j] + tb[j];
        float sg = __builtin_amdgcn_rcpf(1.f + __expf(-sv));
        float e2 = __expf(2.f * tv);
        float th = 1.f - 2.f * __builtin_amdgcn_rcpf(e2 + 1.f);
        zv[j] = sg * th;
      }
      *(uint2*)&z[((size_t)b * HROWS + t) * CCH + ob] = make_uint2(pk2(zv[0], zv[1]), pk2(zv[2], zv[3]));
    }
  }
}

// ---------------- update: [skip_w; res_w] @ z, RMW skip/residual ----------------
// BM=128, BN=128, BK=32, 512 threads. Grid 768 (8 xcd x 96, xcd7 idles 12).
// 3-phase LDS ring (48KB), ONE barrier per step, depth-2 vmcnt(2).
template <int PRE>
__global__ __launch_bounds__(512, 4) void update_kernel(
    const hfu* __restrict__ z, const void* __restrict__ wp,
    const float* __restrict__ skwf, const float* __restrict__ rswf,
    const float* __restrict__ skb, const float* __restrict__ rsb,
    float* __restrict__ skip, float* __restrict__ outf, hfu* __restrict__ outb) {
  __shared__ uint4 sm[3072];  // 48KB: 3 phases x {A 512, B 512}
  const int tid = threadIdx.x;
  const int lane = tid & 63, wid = tid >> 6;
  const int wm = wid >> 1, wn = wid & 1;
  const int lr = lane & 15, lq = lane >> 4;

  const int n = blockIdx.x;                // 768 = 8 xcd * 96
  const int xcd = n & 7, j = n >> 3;       // j 0..95
  const int ttl = j / 12, inner = j % 12;  // 8 local t-tiles x (6 rg x 2 b)
  const int tt = xcd * 8 + ttl;
  if (tt > 62) return;                     // 63 t-tiles total; xcd7 idles 12 blocks
  const int rg = inner >> 1, b = inner & 1;
  const int r0 = rg * 128;                 // 0..640
  const int t0 = tt * 128;

  f32x4 acc[2][4] = {};

  auto stage_u = [&](int ih, int p) {
    const int base = p * 1024;
    const int pr = tid >> 3, w = tid & 7;
    const int row = (pr << 1) | (w & 1);      // 0..127
    const int ck = (w >> 1) ^ (pr & 3);
    const int k0 = ih * 32;
    if (PRE) {
      GLOAD16((const hfu*)wp + (size_t)(r0 + row) * CCH + k0 + ck * 8, &sm[base + tid]);
      GLOAD16(z + ((size_t)b * HROWS + t0 + row) * CCH + k0 + ck * 8, &sm[base + 512 + tid]);
    } else {
      const int R = r0 + row;
      const float* src = (R < SKP) ? (skwf + (size_t)R * CCH + k0 + ck * 8)
                                   : (rswf + (size_t)(R - SKP) * CCH + k0 + ck * 8);
      float4 f0 = *(const float4*)&src[0];
      float4 f1 = *(const float4*)&src[4];
      float v[8] = {f0.x, f0.y, f0.z, f0.w, f1.x, f1.y, f1.z, f1.w};
      sm[base + tid] = pk8(v);
      sm[base + 512 + tid] = *(const uint4*)&z[((size_t)b * HROWS + t0 + row) * CCH + k0 + ck * 8];
    }
  };

  auto compute_u = [&](int p) {
    const int base = p * 1024;
    half8 av[2], bv[4];
#pragma unroll
    for (int mr = 0; mr < 2; ++mr) {
      const int row = wm * 32 + mr * 16 + lr;
      av[mr] = *(const half8*)&sm[base + ldsL(row, lq)];
    }
#pragma unroll
    for (int nr = 0; nr < 4; ++nr) {
      const int row = wn * 64 + nr * 16 + lr;
      bv[nr] = *(const half8*)&sm[base + 512 + ldsL(row, lq)];
    }
#pragma unroll
    for (int mr = 0; mr < 2; ++mr)
#pragma unroll
      for (int nr = 0; nr < 4; ++nr)
        acc[mr][nr] = __builtin_amdgcn_mfma_f32_16x16x32_f16(av[mr], bv[nr], acc[mr][nr], 0, 0, 0);
  };

  if (PRE) {
    stage_u(0, 0);
    stage_u(1, 1);
    for (int ih = 0; ih < 16; ++ih) {
      if (ih < 15)
        asm volatile("s_waitcnt vmcnt(2)" ::: "memory");
      else
        asm volatile("s_waitcnt vmcnt(0)" ::: "memory");
      __builtin_amdgcn_s_barrier();
      __builtin_amdgcn_sched_barrier(0);
      if (ih < 14) stage_u(ih + 2, (ih + 2) % 3);
      __builtin_amdgcn_s_setprio(1);
      compute_u(ih % 3);
      __builtin_amdgcn_s_setprio(0);
      __builtin_amdgcn_sched_barrier(0);
    }
  } else {
    for (int ih = 0; ih < 16; ++ih) {
      stage_u(ih, ih % 3);
      __syncthreads();
      compute_u(ih % 3);
      __syncthreads();
    }
  }

  const bool iskip = (r0 < SKP);
#pragma unroll
  for (int mr = 0; mr < 2; ++mr) {
    const int R = r0 + wm * 32 + mr * 16 + lq * 4;
#pragma unroll
    for (int nr = 0; nr < 4; ++nr) {
      const int t = t0 + wn * 64 + nr * 16 + lr;
      if (t < T_LEN) {
        if (iskip) {
          float4 bb = *(const float4*)&skb[R];
          float4* p = (float4*)&skip[((size_t)b * T_LEN + t) * SKP + R];
          float4 v = *p;
          v.x += acc[mr][nr][0] + bb.x;
          v.y += acc[mr][nr][1] + bb.y;
          v.z += acc[mr][nr][2] + bb.z;
          v.w += acc[mr][nr][3] + bb.w;
          *p = v;
        } else {
          const int rr = R - SKP;
          float4 bb = *(const float4*)&rsb[rr];
          if (PRE) {
            hfu* pb = &outb[((size_t)b * ROWS + PADF + t) * CCH + rr];
            uint2 old = *(uint2*)pb;
            const _Float16* hp = (const _Float16*)&old;
            float v0 = (float)hp[0] + acc[mr][nr][0] + bb.x;
            float v1 = (float)hp[1] + acc[mr][nr][1] + bb.y;
            float v2 = (float)hp[2] + acc[mr][nr][2] + bb.z;
            float v3 = (float)hp[3] + acc[mr][nr][3] + bb.w;
            *(uint2*)pb = make_uint2(pk2(v0, v1), pk2(v2, v3));
          } else {
            float4* p = (float4*)&outf[((size_t)b * ROWS + PADF + t) * CCH + rr];
            float4 v = *p;
            v.x += acc[mr][nr][0] + bb.x;
            v.y += acc[mr][nr][1] + bb.y;
            v.z += acc[mr][nr][2] + bb.z;
            v.w += acc[mr][nr][3] + bb.w;
            *p = v;
          }
        }
      }
    }
  }
}

// ---------------- post1: y1 = relu(W1 @ relu(skip) + b1) -> fp16 ----------------
__global__ __launch_bounds__(256, 2) void post1_kernel(const float* __restrict__ skip,
                                                       const hfu* __restrict__ w,
                                                       const float* __restrict__ bias,
                                                       hfu* __restrict__ y1) {
  __shared__ uint4 sm[2048];
  uint4* sA = sm;
  uint4* sB = sm + 1024;
  const int tid = threadIdx.x;
  const int lane = tid & 63, wid = tid >> 6;
  const int wm = wid >> 1, wn = wid & 1;
  const int lr = lane & 15, lq = lane >> 4;
  const int t0 = blockIdx.x * 128;
  const int r0 = blockIdx.y * 128;
  const int b = blockIdx.z;
  f32x4 acc[4][4] = {};
  for (int kt = 0; kt < 4; ++kt) {  // K=256
#pragma unroll
    for (int c = 0; c < 4; ++c) {
      const int cb = c * 256 + wid * 64;
      const int ch = cb + lane;
      const int ksub = ch >> 7, mn = ch & 127;
      const int k0 = kt * 64 + ksub * 8;
      GLOAD16(w + (size_t)(r0 + mn) * SKP + k0, &sA[cb]);
      int row = t0 + mn;
      if (row > T_LEN - 1) row = T_LEN - 1;
      const float* src = skip + ((size_t)b * T_LEN + row) * SKP + k0;
      float4 f0 = *(const float4*)&src[0];
      float4 f1 = *(const float4*)&src[4];
      float v[8] = {fmaxf(f0.x, 0.f), fmaxf(f0.y, 0.f), fmaxf(f0.z, 0.f), fmaxf(f0.w, 0.f),
                    fmaxf(f1.x, 0.f), fmaxf(f1.y, 0.f), fmaxf(f1.z, 0.f), fmaxf(f1.w, 0.f)};
      sB[ch] = pk8(v);
    }
    __syncthreads();
#pragma unroll
    for (int ks = 0; ks < 2; ++ks) {
      const int kb = (ks * 4 + lq) * 128;
      half8 av[4], bv[4];
#pragma unroll
      for (int r = 0; r < 4; ++r) {
        av[r] = *(const half8*)&sA[kb + wm * 64 + r * 16 + lr];
        bv[r] = *(const half8*)&sB[kb + wn * 64 + r * 16 + lr];
      }
#pragma unroll
      for (int mr = 0; mr < 4; ++mr)
#pragma unroll
        for (int nr = 0; nr < 4; ++nr)
          acc[mr][nr] = __builtin_amdgcn_mfma_f32_16x16x32_f16(av[mr], bv[nr], acc[mr][nr], 0, 0, 0);
    }
    __syncthreads();
  }
#pragma unroll
  for (int mr = 0; mr < 4; ++mr) {
    const int ob = r0 + wm * 64 + mr * 16 + lq * 4;
    float4 bb = *(const float4*)&bias[ob];
    const float bs[4] = {bb.x, bb.y, bb.z, bb.w};
#pragma unroll
    for (int nr = 0; nr < 4; ++nr) {
      const int t = t0 + wn * 64 + nr * 16 + lr;
      float v[4];
#pragma unroll
      for (int j = 0; j < 4; ++j) v[j] = fmaxf(acc[mr][nr][j] + bs[j], 0.f);
      *(uint2*)&y1[((size_t)b * HROWS + t) * SKP + ob] = make_uint2(pk2(v[0], v[1]), pk2(v[2], v[3]));
    }
  }
}

// ---------------- post2: out = W2 @ y1 + b2 -> d_out [b][t][q] fp32 ----------------
__global__ __launch_bounds__(256, 2) void post2_kernel(const hfu* __restrict__ y1,
                                                       const hfu* __restrict__ w,
                                                       const float* __restrict__ bias,
                                                       float* __restrict__ outp) {
  __shared__ uint4 sm[2048];
  uint4* sA = sm;
  uint4* sB = sm + 1024;
  const int tid = threadIdx.x;
  const int lane = tid & 63, wid = tid >> 6;
  const int wm = wid >> 1, wn = wid & 1;
  const int lr = lane & 15, lq = lane >> 4;
  const int t0 = blockIdx.x * 128;
  const int r0 = blockIdx.y * 128;
  const int b = blockIdx.z;
  f32x4 acc[4][4] = {};
  for (int kt = 0; kt < 4; ++kt) {
#pragma unroll
    for (int c = 0; c < 4; ++c) {
      const int cb = c * 256 + wid * 64;
      const int ch = cb + lane;
      const int ksub = ch >> 7, mn = ch & 127;
      const int k0 = kt * 64 + ksub * 8;
      GLOAD16(w + (size_t)(r0 + mn) * SKP + k0, &sA[cb]);
      GLOAD16(y1 + ((size_t)b * HROWS + t0 + mn) * SKP + k0, &sB[cb]);
    }
    __syncthreads();
#pragma unroll
    for (int ks = 0; ks < 2; ++ks) {
      const int kb = (ks * 4 + lq) * 128;
      half8 av[4], bv[4];
#pragma unroll
      for (int r = 0; r < 4; ++r) {
        av[r] = *(const half8*)&sA[kb + wm * 64 + r * 16 + lr];
        bv[r] = *(const half8*)&sB[kb + wn * 64 + r * 16 + lr];
      }
#pragma unroll
      for (int mr = 0; mr < 4; ++mr)
#pragma unroll
        for (int nr = 0; nr < 4; ++nr)
          acc[mr][nr] = __builtin_amdgcn_mfma_f32_16x16x32_f16(av[mr], bv[nr], acc[mr][nr], 0, 0, 0);
    }
    __syncthreads();
  }
#pragma unroll
  for (int mr = 0; mr < 4; ++mr) {
    const int ob = r0 + wm * 64 + mr * 16 + lq * 4;
    float4 bb = *(const float4*)&bias[ob];
#pragma unroll
    for (int nr = 0; nr < 4; ++nr) {
      const int t = t0 + wn * 64 + nr * 16 + lr;
      if (t < T_LEN) {
        float4 v;
        v.x = acc[mr][nr][0] + bb.x;
        v.y = acc[mr][nr][1] + bb.y;
        v.z = acc[mr][nr][2] + bb.z;
        v.w = acc[mr][nr][3] + bb.w;
        *(float4*)&outp[((size_t)b * T_LEN + t) * NQ + ob] = v;
      }
    }
  }
}

extern "C" void kernel_launch(void* const* d_in, const int* in_sizes, int n_in,
                              void* d_out, int out_size, void* d_ws, size_t ws_size,
                              hipStream_t stream) {
  const int* x = (const int*)d_in[0];
  const float* h = (const float*)d_in[1];
  const float* causal_w = (const float*)d_in[2];
  const float* causal_b = (const float*)d_in[3];
  const float* dil_sig_w = (const float*)d_in[4];
  const float* dil_sig_b = (const float*)d_in[5];
  const float* dil_tanh_w = (const float*)d_in[6];
  const float* dil_tanh_b = (const float*)d_in[7];
  const float* aux_sig_w = (const float*)d_in[8];
  const float* aux_sig_b = (const float*)d_in[9];
  const float* aux_tanh_w = (const float*)d_in[10];
  const float* aux_tanh_b = (const float*)d_in[11];
  const float* skip_w = (const float*)d_in[12];
  const float* skip_b = (const float*)d_in[13];
  const float* res_w = (const float*)d_in[14];
  const float* res_b = (const float*)d_in[15];
  const float* post1_w = (const float*)d_in[16];
  const float* post1_b = (const float*)d_in[17];
  const float* post2_w = (const float*)d_in[18];
  const float* post2_b = (const float*)d_in[19];
  float* outp = (float*)d_out;

  char* p = (char*)d_ws;
  auto alloc = [&](size_t bytes) {
    char* r = p;
    p += (bytes + 255) & ~(size_t)255;
    return r;
  };
  float* outf = (float*)alloc((size_t)BATCH * ROWS * CCH * 4);   // fp32 residual (PRE=0 only)
  float* skip = (float*)alloc((size_t)BATCH * T_LEN * SKP * 4);  // fp32 skip accumulator
  hfu* zb = (hfu*)alloc((size_t)BATCH * HROWS * CCH * 2);        // z fp16 (reused as y1)
  hfu* hbf = (hfu*)alloc((size_t)BATCH * HROWS * AUXP * 2);
  hfu* auxsb = (hfu*)alloc((size_t)NLAYER * CCH * AUXP * 2);
  hfu* auxtb = (hfu*)alloc((size_t)NLAYER * CCH * AUXP * 2);
  hfu* p1b = (hfu*)alloc((size_t)NQ * SKP * 2);
  hfu* p2b = (hfu*)alloc((size_t)NQ * SKP * 2);
  float* cwt = (float*)alloc((size_t)2 * NQ * CCH * 4);          // transposed causal_w
  hfu* y1 = zb;
  // optional (PRE) region
  hfu* outb = (hfu*)alloc((size_t)BATCH * ROWS * CCH * 2);       // fp16 residual master (PRE)
  hfu* dilS = (hfu*)alloc((size_t)NLAYER * 2 * CCH * CCH * 2);
  hfu* dilT = (hfu*)alloc((size_t)NLAYER * 2 * CCH * CCH * 2);
  hfu* wsr = (hfu*)alloc((size_t)NLAYER * 768 * CCH * 2);
  const bool pre = ((size_t)(p - (char*)d_ws) <= ws_size);

  // weight conversions
  cvt_aux<<<256, 256, 0, stream>>>(aux_sig_w, auxsb);
  cvt_aux<<<256, 256, 0, stream>>>(aux_tanh_w, auxtb);
  cvt_copy<<<64, 256, 0, stream>>>(post1_w, p1b, NQ * SKP);
  cvt_copy<<<64, 256, 0, stream>>>(post2_w, p2b, NQ * SKP);
  cvt_cwt<<<1024, 256, 0, stream>>>(causal_w, cwt);
  if (pre) {
    cvt_dil<<<2048, 256, 0, stream>>>(dil_sig_w, dilS);
    cvt_dil<<<2048, 256, 0, stream>>>(dil_tanh_w, dilT);
    cvt_skipres<<<2048, 256, 0, stream>>>(skip_w, res_w, wsr);
  }

  // zero: skip + padded rows of the residual master in use
  zero16<<<512, 256, 0, stream>>>((uint4*)skip, (int)((size_t)BATCH * T_LEN * SKP * 4 / 16));
  for (int b = 0; b < BATCH; ++b) {
    if (pre) {
      zero16<<<32, 256, 0, stream>>>((uint4*)(outb + (size_t)b * ROWS * CCH), PADF * CCH * 2 / 16);
      zero16<<<48, 256, 0, stream>>>((uint4*)(outb + ((size_t)b * ROWS + PADF + T_LEN) * CCH),
                                     (TPAD - T_LEN) * CCH * 2 / 16);
    } else {
      zero16<<<64, 256, 0, stream>>>((uint4*)(outf + (size_t)b * ROWS * CCH), PADF * CCH * 4 / 16);
      zero16<<<96, 256, 0, stream>>>((uint4*)(outf + ((size_t)b * ROWS + PADF + T_LEN) * CCH),
                                     (TPAD - T_LEN) * CCH * 4 / 16);
    }
  }

  htrans_kernel<<<dim3(128, 2), 256, 0, stream>>>(h, hbf);
  if (pre)
    embed_kernel<1><<<dim3(2000, 2), 256, 0, stream>>>(x, cwt, causal_b, nullptr, outb);
  else
    embed_kernel<0><<<dim3(2000, 2), 256, 0, stream>>>(x, cwt, causal_b, outf, nullptr);

  for (int l = 0; l < NLAYER; ++l) {
    const int d = 1 << (l % 10);
    if (pre) {
      gate_kernel<1><<<512, 512, 0, stream>>>(
          outb, nullptr, hbf, dilS + (size_t)l * 2 * CCH * CCH, dilT + (size_t)l * 2 * CCH * CCH,
          auxsb + (size_t)l * CCH * AUXP, auxtb + (size_t)l * CCH * AUXP,
          dil_sig_b + (size_t)l * CCH, aux_sig_b + (size_t)l * CCH,
          dil_tanh_b + (size_t)l * CCH, aux_tanh_b + (size_t)l * CCH, zb, d);
      update_kernel<1><<<768, 512, 0, stream>>>(
          zb, wsr + (size_t)l * 768 * CCH, nullptr, nullptr,
          skip_b + (size_t)l * SKP, res_b + (size_t)l * CCH, skip, nullptr, outb);
    } else {
      gate_kernel<0><<<512, 512, 0, stream>>>(
          nullptr, outf, hbf, dil_sig_w + (size_t)l * CCH * CCH * 2,
          dil_tanh_w + (size_t)l * CCH * CCH * 2,
          auxsb + (size_t)l * CCH * AUXP, auxtb + (size_t)l * CCH * AUXP,
          dil_sig_b + (size_t)l * CCH, aux_sig_b + (size_t)l * CCH,
          dil_tanh_b + (size_t)l * CCH, aux_tanh_b + (size_t)l * CCH, zb, d);
      update_kernel<0><<<768, 512, 0, stream>>>(
          zb, nullptr, skip_w + (size_t)l * SKP * CCH, res_w + (size_t)l * CCH * CCH,
          skip_b + (size_t)l * SKP, res_b + (size_t)l * CCH, skip, outf, nullptr);
    }
  }

  post1_kernel<<<dim3(63, 2, BATCH), 256, 0, stream>>>(skip, p1b, post1_b, y1);
  post2_kernel<<<dim3(63, 2, BATCH), 256, 0, stream>>>(y1, p2b, post2_b, outp);
}

// Round 12
// 2087.302 us; speedup vs baseline: 1.0562x; 1.0562x over previous
//
#include <hip/hip_runtime.h>
#include <math.h>

#define T_LEN 8000
#define BATCH 2
#define CCH 512
#define SKP 256
#define AUXP 32
#define NQ 256
#define NLAYER 30
#define PADF 512
#define TPAD 8192
#define ROWS (PADF + TPAD)         // 8704 padded rows
#define HROWS TPAD                 // 8192 rows (z, h, y1)

typedef unsigned short hfu;        // fp16 as raw bits
typedef unsigned int u32;
typedef __attribute__((ext_vector_type(8))) _Float16 half8;
typedef __attribute__((ext_vector_type(4))) float f32x4;

#define GLOAD16(g, l)                                                          \
  __builtin_amdgcn_global_load_lds(                                            \
      (const __attribute__((address_space(1))) void*)(g),                      \
      (__attribute__((address_space(3))) void*)(l), 16, 0, 0)

__device__ inline hfu hfbits(float f) {
  union { _Float16 h; hfu u; } x;
  x.h = (_Float16)f;
  return x.u;
}
__device__ inline u32 pk2(float a, float b) {
  return (u32)hfbits(a) | ((u32)hfbits(b) << 16);
}
__device__ inline uint4 pk8(const float f[8]) {
  return make_uint4(pk2(f[0], f[1]), pk2(f[2], f[3]), pk2(f[4], f[5]), pk2(f[6], f[7]));
}
// pair-interleaved XOR LDS layout for BK=32 tiles (4 chunks/row), update kernel.
__device__ inline int ldsL(int row, int ck) {
  return ((row >> 1) << 3) + ((((ck) ^ ((row >> 1) & 3)) << 1) | (row & 1));
}

// ---------------- utility: zero / converts ----------------
__global__ __launch_bounds__(256) void zero16(uint4* p, int n) {
  for (int i = blockIdx.x * 256 + threadIdx.x; i < n; i += gridDim.x * 256)
    p[i] = make_uint4(0u, 0u, 0u, 0u);
}

// dil weights: [30][512][512][2] f32 -> [30][2][512][512] fp16, sig+tanh in one launch
__global__ __launch_bounds__(256) void cvt_dil2(const float* __restrict__ inS,
                                                const float* __restrict__ inT,
                                                hfu* __restrict__ outS, hfu* __restrict__ outT) {
  const long NG = (long)NLAYER * CCH * (CCH / 4);
  for (long g2 = (long)blockIdx.x * 256 + threadIdx.x; g2 < 2 * NG; g2 += (long)gridDim.x * 256) {
    const int sel = (int)(g2 >= NG);
    const long g = sel ? (g2 - NG) : g2;
    const float* in = sel ? inT : inS;
    hfu* out = sel ? outT : outS;
    const int i4 = (int)(g & 127) * 4;
    const int o = (int)((g >> 7) & 511);
    const int l = (int)(g >> 16);
    const float* pp = in + (((size_t)l * CCH + o) * CCH + i4) * 2;
    float4 f0 = *(const float4*)pp;
    float4 f1 = *(const float4*)(pp + 4);
    uint2 t0 = make_uint2(pk2(f0.x, f0.z), pk2(f1.x, f1.z));
    uint2 t1 = make_uint2(pk2(f0.y, f0.w), pk2(f1.y, f1.w));
    hfu* ob = out + ((size_t)l * 2 * CCH + o) * CCH + i4;
    *(uint2*)ob = t0;
    *(uint2*)(ob + (size_t)CCH * CCH) = t1;
  }
}

// skip_w [30][256][512] + res_w [30][512][512] -> stacked [30][768][512] fp16
__global__ __launch_bounds__(256) void cvt_skipres(const float* __restrict__ skw,
                                                   const float* __restrict__ rsw,
                                                   hfu* __restrict__ out) {
  const long NG = (long)NLAYER * 768 * (CCH / 4);
  for (long g = (long)blockIdx.x * 256 + threadIdx.x; g < NG; g += (long)gridDim.x * 256) {
    const int i4 = (int)(g & 127) * 4;
    const int r = (int)((g >> 7) % 768);
    const int l = (int)(g / (128 * 768));
    const float* src = (r < SKP) ? (skw + ((size_t)l * SKP + r) * CCH + i4)
                                 : (rsw + ((size_t)l * CCH + (r - SKP)) * CCH + i4);
    float4 f = *(const float4*)src;
    *(uint2*)(out + ((size_t)l * 768 + r) * CCH + i4) = make_uint2(pk2(f.x, f.y), pk2(f.z, f.w));
  }
}

// aux weights [30][512][28] -> [30][512][32] fp16 zero-padded
__global__ __launch_bounds__(256) void cvt_aux(const float* __restrict__ in, hfu* __restrict__ out) {
  const int N = NLAYER * CCH * AUXP;
  for (int i = blockIdx.x * 256 + threadIdx.x; i < N; i += gridDim.x * 256) {
    const int j = i & 31;
    const int o = (i >> 5) & 511;
    const int l = i >> 14;
    float v = (j < 28) ? in[((size_t)l * CCH + o) * 28 + j] : 0.f;
    out[i] = hfbits(v);
  }
}

__global__ __launch_bounds__(256) void cvt_copy(const float* __restrict__ in, hfu* __restrict__ out, int n) {
  for (int i = blockIdx.x * 256 + threadIdx.x; i < n; i += gridDim.x * 256)
    out[i] = hfbits(in[i]);
}

// causal_w [512][256][2] f32 -> cwt [2][256][512] f32 (transposed for coalesced embed)
__global__ __launch_bounds__(256) void cvt_cwt(const float* __restrict__ cw, float* __restrict__ out) {
  const int N = 2 * NQ * CCH;
  for (int i = blockIdx.x * 256 + threadIdx.x; i < N; i += gridDim.x * 256) {
    const int tap = i >> 17;
    const int r = i & 131071;
    const int xq = r >> 9;
    const int o = r & 511;
    out[i] = cw[((size_t)o * NQ + xq) * 2 + tap];
  }
}

// h [b][28][8000] f32 -> [b][8192][32] fp16 zero-padded
__global__ __launch_bounds__(256) void htrans_kernel(const float* __restrict__ h, hfu* __restrict__ hbf) {
  const int b = blockIdx.y;
  const int t = blockIdx.x * 64 + (threadIdx.x & 63);
  const int j0 = threadIdx.x >> 6;
#pragma unroll
  for (int j = j0; j < AUXP; j += 4) {
    float v = (j < 28 && t < T_LEN) ? h[((size_t)b * 28 + j) * T_LEN + t] : 0.f;
    hbf[((size_t)b * HROWS + t) * AUXP + j] = hfbits(v);
  }
}

// ---------------- embed (coalesced via cwt) ----------------
template <int PRE>
__global__ __launch_bounds__(256) void embed_kernel(const int* __restrict__ x,
                                                    const float* __restrict__ cwt,
                                                    const float* __restrict__ cb,
                                                    float* __restrict__ outf,
                                                    hfu* __restrict__ outb) {
  const int b = blockIdx.y;
  const int t = blockIdx.x * 4 + (threadIdx.x >> 6);
  const int o = (threadIdx.x & 63) * 8;
  const int xc = x[(size_t)b * T_LEN + t] & 255;
  const int xp = (t > 0) ? (x[(size_t)b * T_LEN + t - 1] & 255) : 0;
  const float won = (t > 0) ? 1.f : 0.f;
  const float* c1 = cwt + 131072 + (size_t)xc * CCH + o;
  const float* c0 = cwt + (size_t)xp * CCH + o;
  float v[8];
#pragma unroll
  for (int j = 0; j < 8; ++j) v[j] = cb[o + j] + c1[j] + won * c0[j];
  if (PRE) {
    *(uint4*)&outb[((size_t)b * ROWS + PADF + t) * CCH + o] = pk8(v);
  } else {
    float* po = outf + ((size_t)b * ROWS + PADF + t) * CCH + o;
    *(float4*)po = make_float4(v[0], v[1], v[2], v[3]);
    *(float4*)(po + 4) = make_float4(v[4], v[5], v[6], v[7]);
  }
}

// ---------------- gate: sig/tanh dilated GEMMs + aux + gating ----------------
// BM=128, BN=256, BK=64: 17 K-steps (16 dil + 1 aux). 512 threads (8 waves:
// wm2 x wn4, mr4 x nr4). Grid 256 = 1 block/CU (xcd owns t [xcd*1024,...)).
// 2-phase x 64KB = 128KB DYNAMIC LDS, counted vmcnt(8)/(4)/(0).
// Row layout: 8 chunks of 16B per row, chunk swizzle ck^(row&7) (R8-proven).
template <int PRE>
__global__ __launch_bounds__(512, 2) void gate_kernel(
    const hfu* __restrict__ actb, const float* __restrict__ actf,
    const hfu* __restrict__ hbf,
    const void* __restrict__ wsp, const void* __restrict__ wtp,
    const hfu* __restrict__ auxs, const hfu* __restrict__ auxt,
    const float* __restrict__ bs1, const float* __restrict__ bs2,
    const float* __restrict__ bt1, const float* __restrict__ bt2,
    hfu* __restrict__ z, int d) {
  extern __shared__ uint4 smd[];  // 2 phases x {As 1024, At 1024, B 2048} uint4
  const int tid = threadIdx.x;
  const int lane = tid & 63, wid = tid >> 6;
  const int wm = wid >> 2, wn = wid & 3;
  const int lr = lane & 15, lq = lane >> 4;

  const int n = blockIdx.x;               // 256 = 8 xcd * 32
  const int f = (n & 7) * 32 + (n >> 3);
  const int tt = f >> 3, inner = f & 7;   // 32 t-tiles x (4 og x 2 b)
  const int o0 = (inner >> 1) * 128;
  const int b = inner & 1;
  const int t0 = tt * 256;

  f32x4 accS[4][4] = {};
  f32x4 accT[4][4] = {};

  // dil K-step ih (0..15; ih<8 -> tau=1): 8 loads/thread (As 2, At 2, B 4)
  auto stage_dil = [&](int ih, int p) {
    const int base = p * 4096;
    const int tau = (ih < 8) ? 1 : 0;
    const int koff = (ih & 7) * 64;
    if (PRE) {
#pragma unroll
      for (int c = 0; c < 2; ++c) {
        const int s = c * 512 + tid;
        const int row = s >> 3, ck = (s & 7) ^ (row & 7);
        const size_t wo = ((size_t)tau * CCH + o0 + row) * CCH + koff + ck * 8;
        GLOAD16((const hfu*)wsp + wo, &smd[base + s]);
        GLOAD16((const hfu*)wtp + wo, &smd[base + 1024 + s]);
      }
#pragma unroll
      for (int c = 0; c < 4; ++c) {
        const int s = c * 512 + tid;
        const int row = s >> 3, ck = (s & 7) ^ (row & 7);
        const hfu* ar = actb + ((size_t)b * ROWS + PADF + t0 + row - (tau ? 0 : d)) * CCH + koff + ck * 8;
        GLOAD16(ar, &smd[base + 2048 + s]);
      }
    } else {
      const float* wsf = (const float*)wsp;
      const float* wtf = (const float*)wtp;
#pragma unroll
      for (int c = 0; c < 2; ++c) {
        const int s = c * 512 + tid;
        const int row = s >> 3, ck = (s & 7) ^ (row & 7);
        const size_t fb = ((size_t)(o0 + row) * CCH + koff + ck * 8) * 2;
        float vs[8], vt[8];
#pragma unroll
        for (int j = 0; j < 4; ++j) {
          float4 fs = *(const float4*)&wsf[fb + j * 4];
          float4 ft = *(const float4*)&wtf[fb + j * 4];
          vs[2 * j] = tau ? fs.y : fs.x;
          vs[2 * j + 1] = tau ? fs.w : fs.z;
          vt[2 * j] = tau ? ft.y : ft.x;
          vt[2 * j + 1] = tau ? ft.w : ft.z;
        }
        smd[base + s] = pk8(vs);
        smd[base + 1024 + s] = pk8(vt);
      }
#pragma unroll
      for (int c = 0; c < 4; ++c) {
        const int s = c * 512 + tid;
        const int row = s >> 3, ck = (s & 7) ^ (row & 7);
        const float* ar = actf + ((size_t)b * ROWS + PADF + t0 + row - (tau ? 0 : d)) * CCH + koff + ck * 8;
        float4 f0 = *(const float4*)&ar[0];
        float4 f1 = *(const float4*)&ar[4];
        float vb[8] = {f0.x, f0.y, f0.z, f0.w, f1.x, f1.y, f1.z, f1.w};
        smd[base + 2048 + s] = pk8(vb);
      }
    }
  };

  // aux step (K=32, 4 chunks/row, swizzle ck^(row&3)): 4 loads/thread
  auto stage_aux = [&](int p) {
    const int base = p * 4096;
    {
      const int row = tid >> 2, ck = (tid & 3) ^ (row & 3);
      if (PRE) {
        GLOAD16(auxs + (size_t)(o0 + row) * AUXP + ck * 8, &smd[base + tid]);
        GLOAD16(auxt + (size_t)(o0 + row) * AUXP + ck * 8, &smd[base + 1024 + tid]);
      } else {
        smd[base + tid] = *(const uint4*)&auxs[(size_t)(o0 + row) * AUXP + ck * 8];
        smd[base + 1024 + tid] = *(const uint4*)&auxt[(size_t)(o0 + row) * AUXP + ck * 8];
      }
    }
#pragma unroll
    for (int c = 0; c < 2; ++c) {
      const int s = c * 512 + tid;
      const int row = s >> 2, ck = (s & 3) ^ (row & 3);
      if (PRE)
        GLOAD16(hbf + ((size_t)b * HROWS + t0 + row) * AUXP + ck * 8, &smd[base + 2048 + s]);
      else
        smd[base + 2048 + s] = *(const uint4*)&hbf[((size_t)b * HROWS + t0 + row) * AUXP + ck * 8];
    }
  };

  // one K=64 step: 24 ds_read_b128, 64 MFMAs per wave (kk-split for liveness)
  auto compute_dil = [&](int p) {
    const int base = p * 4096;
#pragma unroll
    for (int kk = 0; kk < 2; ++kk) {
      half8 af[4], ag[4], bv[4];
#pragma unroll
      for (int mr = 0; mr < 4; ++mr) {
        const int row = wm * 64 + mr * 16 + lr;
        const int idx = row * 8 + ((kk * 4 + lq) ^ (row & 7));
        af[mr] = *(const half8*)&smd[base + idx];
        ag[mr] = *(const half8*)&smd[base + 1024 + idx];
      }
#pragma unroll
      for (int nr = 0; nr < 4; ++nr) {
        const int row = wn * 64 + nr * 16 + lr;
        bv[nr] = *(const half8*)&smd[base + 2048 + row * 8 + ((kk * 4 + lq) ^ (row & 7))];
      }
#pragma unroll
      for (int mr = 0; mr < 4; ++mr)
#pragma unroll
        for (int nr = 0; nr < 4; ++nr) {
          accS[mr][nr] = __builtin_amdgcn_mfma_f32_16x16x32_f16(af[mr], bv[nr], accS[mr][nr], 0, 0, 0);
          accT[mr][nr] = __builtin_amdgcn_mfma_f32_16x16x32_f16(ag[mr], bv[nr], accT[mr][nr], 0, 0, 0);
        }
    }
  };

  auto compute_aux = [&](int p) {
    const int base = p * 4096;
    half8 af[4], ag[4], bv[4];
#pragma unroll
    for (int mr = 0; mr < 4; ++mr) {
      const int row = wm * 64 + mr * 16 + lr;
      const int idx = row * 4 + (lq ^ (row & 3));
      af[mr] = *(const half8*)&smd[base + idx];
      ag[mr] = *(const half8*)&smd[base + 1024 + idx];
    }
#pragma unroll
    for (int nr = 0; nr < 4; ++nr) {
      const int row = wn * 64 + nr * 16 + lr;
      bv[nr] = *(const half8*)&smd[base + 2048 + row * 4 + (lq ^ (row & 3))];
    }
#pragma unroll
    for (int mr = 0; mr < 4; ++mr)
#pragma unroll
      for (int nr = 0; nr < 4; ++nr) {
        accS[mr][nr] = __builtin_amdgcn_mfma_f32_16x16x32_f16(af[mr], bv[nr], accS[mr][nr], 0, 0, 0);
        accT[mr][nr] = __builtin_amdgcn_mfma_f32_16x16x32_f16(ag[mr], bv[nr], accT[mr][nr], 0, 0, 0);
      }
  };

  if (PRE) {
    stage_dil(0, 0);
    for (int ih = 0; ih < 17; ++ih) {
      if (ih < 15) {
        stage_dil(ih + 1, (ih + 1) & 1);
        asm volatile("s_waitcnt vmcnt(8)" ::: "memory");  // step-ih's 8 loads landed
      } else if (ih == 15) {
        stage_aux(0);                                     // phase 16&1 = 0
        asm volatile("s_waitcnt vmcnt(4)" ::: "memory");
      } else {
        asm volatile("s_waitcnt vmcnt(0)" ::: "memory");
      }
      __builtin_amdgcn_s_barrier();
      __builtin_amdgcn_sched_barrier(0);
      __builtin_amdgcn_s_setprio(1);
      if (ih < 16) compute_dil(ih & 1); else compute_aux(0);
      __builtin_amdgcn_s_setprio(0);
      __builtin_amdgcn_sched_barrier(0);
      __builtin_amdgcn_s_barrier();
    }
  } else {
    for (int ih = 0; ih < 17; ++ih) {
      if (ih < 16) stage_dil(ih, ih & 1); else stage_aux(0);
      __syncthreads();
      if (ih < 16) compute_dil(ih & 1); else compute_aux(0);
      __syncthreads();
    }
  }

  // epilogue: bias + sigmoid*tanh -> z fp16 [b][t][ch]
#pragma unroll
  for (int mr = 0; mr < 4; ++mr) {
    const int ob = o0 + wm * 64 + mr * 16 + lq * 4;
    float4 x1 = *(const float4*)&bs1[ob];
    float4 x2 = *(const float4*)&bs2[ob];
    float4 y1 = *(const float4*)&bt1[ob];
    float4 y2 = *(const float4*)&bt2[ob];
    const float sb[4] = {x1.x + x2.x, x1.y + x2.y, x1.z + x2.z, x1.w + x2.w};
    const float tb[4] = {y1.x + y2.x, y1.y + y2.y, y1.z + y2.z, y1.w + y2.w};
#pragma unroll
    for (int nr = 0; nr < 4; ++nr) {
      const int t = t0 + wn * 64 + nr * 16 + lr;
      float zv[4];
#pragma unroll
      for (int j = 0; j < 4; ++j) {
        float sv = accS[mr][nr][j] + sb[j];
        float tv = accT[mr][nr][j] + tb[j];
        float sg = __builtin_amdgcn_rcpf(1.f + __expf(-sv));
        float e2 = __expf(2.f * tv);
        float th = 1.f - 2.f * __builtin_amdgcn_rcpf(e2 + 1.f);
        zv[j] = sg * th;
      }
      *(uint2*)&z[((size_t)b * HROWS + t) * CCH + ob] = make_uint2(pk2(zv[0], zv[1]), pk2(zv[2], zv[3]));
    }
  }
}

// ---------------- update: [skip_w; res_w] @ z, RMW skip/residual ----------------
// BM=128, BN=128, BK=32, 512 threads, grid 768 (xcd owns tt [xcd*8,...)).
// 2-phase 32KB LDS, vmcnt(2). PRE: residual AND skip are fp16 RMW.
template <int PRE>
__global__ __launch_bounds__(512, 4) void update_kernel(
    const hfu* __restrict__ z, const void* __restrict__ wp,
    const float* __restrict__ skwf, const float* __restrict__ rswf,
    const float* __restrict__ skb, const float* __restrict__ rsb,
    float* __restrict__ skip, hfu* __restrict__ skiph,
    float* __restrict__ outf, hfu* __restrict__ outb) {
  __shared__ uint4 sm[2048];  // 32KB: 2 phases x {A 512, B 512}
  const int tid = threadIdx.x;
  const int lane = tid & 63, wid = tid >> 6;
  const int wm = wid >> 1, wn = wid & 1;
  const int lr = lane & 15, lq = lane >> 4;

  const int n = blockIdx.x;                // 768 = 8 xcd * 96
  const int xcd = n & 7, j = n >> 3;       // j 0..95
  const int ttl = j / 12, inner = j % 12;  // 8 local t-tiles x (6 rg x 2 b)
  const int tt = xcd * 8 + ttl;
  if (tt > 62) return;                     // 63 t-tiles; xcd7 idles 12 blocks
  const int rg = inner >> 1, b = inner & 1;
  const int r0 = rg * 128;                 // 0..640
  const int t0 = tt * 128;

  f32x4 acc[2][4] = {};

  auto stage_u = [&](int ih, int p) {
    const int base = p * 1024;
    const int pr = tid >> 3, w = tid & 7;
    const int row = (pr << 1) | (w & 1);      // 0..127
    const int ck = (w >> 1) ^ (pr & 3);
    const int k0 = ih * 32;
    if (PRE) {
      GLOAD16((const hfu*)wp + (size_t)(r0 + row) * CCH + k0 + ck * 8, &sm[base + tid]);
      GLOAD16(z + ((size_t)b * HROWS + t0 + row) * CCH + k0 + ck * 8, &sm[base + 512 + tid]);
    } else {
      const int R = r0 + row;
      const float* src = (R < SKP) ? (skwf + (size_t)R * CCH + k0 + ck * 8)
                                   : (rswf + (size_t)(R - SKP) * CCH + k0 + ck * 8);
      float4 f0 = *(const float4*)&src[0];
      float4 f1 = *(const float4*)&src[4];
      float v[8] = {f0.x, f0.y, f0.z, f0.w, f1.x, f1.y, f1.z, f1.w};
      sm[base + tid] = pk8(v);
      sm[base + 512 + tid] = *(const uint4*)&z[((size_t)b * HROWS + t0 + row) * CCH + k0 + ck * 8];
    }
  };

  auto compute_u = [&](int p) {
    const int base = p * 1024;
    half8 av[2], bv[4];
#pragma unroll
    for (int mr = 0; mr < 2; ++mr) {
      const int row = wm * 32 + mr * 16 + lr;
      av[mr] = *(const half8*)&sm[base + ldsL(row, lq)];
    }
#pragma unroll
    for (int nr = 0; nr < 4; ++nr) {
      const int row = wn * 64 + nr * 16 + lr;
      bv[nr] = *(const half8*)&sm[base + 512 + ldsL(row, lq)];
    }
#pragma unroll
    for (int mr = 0; mr < 2; ++mr)
#pragma unroll
      for (int nr = 0; nr < 4; ++nr)
        acc[mr][nr] = __builtin_amdgcn_mfma_f32_16x16x32_f16(av[mr], bv[nr], acc[mr][nr], 0, 0, 0);
  };

  if (PRE) {
    stage_u(0, 0);
    for (int ih = 0; ih < 16; ++ih) {
      if (ih < 15) {
        stage_u(ih + 1, (ih + 1) & 1);
        asm volatile("s_waitcnt vmcnt(2)" ::: "memory");
      } else {
        asm volatile("s_waitcnt vmcnt(0)" ::: "memory");
      }
      __builtin_amdgcn_s_barrier();
      __builtin_amdgcn_sched_barrier(0);
      __builtin_amdgcn_s_setprio(1);
      compute_u(ih & 1);
      __builtin_amdgcn_s_setprio(0);
      __builtin_amdgcn_sched_barrier(0);
      __builtin_amdgcn_s_barrier();
    }
  } else {
    for (int ih = 0; ih < 16; ++ih) {
      stage_u(ih, ih & 1);
      __syncthreads();
      compute_u(ih & 1);
      __syncthreads();
    }
  }

  const bool iskip = (r0 < SKP);
#pragma unroll
  for (int mr = 0; mr < 2; ++mr) {
    const int R = r0 + wm * 32 + mr * 16 + lq * 4;
#pragma unroll
    for (int nr = 0; nr < 4; ++nr) {
      const int t = t0 + wn * 64 + nr * 16 + lr;
      if (t < T_LEN) {
        if (iskip) {
          float4 bb = *(const float4*)&skb[R];
          if (PRE) {
            hfu* ps = &skiph[((size_t)b * T_LEN + t) * SKP + R];
            uint2 old = *(uint2*)ps;
            const _Float16* hp = (const _Float16*)&old;
            float v0 = (float)hp[0] + acc[mr][nr][0] + bb.x;
            float v1 = (float)hp[1] + acc[mr][nr][1] + bb.y;
            float v2 = (float)hp[2] + acc[mr][nr][2] + bb.z;
            float v3 = (float)hp[3] + acc[mr][nr][3] + bb.w;
            *(uint2*)ps = make_uint2(pk2(v0, v1), pk2(v2, v3));
          } else {
            float4* p = (float4*)&skip[((size_t)b * T_LEN + t) * SKP + R];
            float4 v = *p;
            v.x += acc[mr][nr][0] + bb.x;
            v.y += acc[mr][nr][1] + bb.y;
            v.z += acc[mr][nr][2] + bb.z;
            v.w += acc[mr][nr][3] + bb.w;
            *p = v;
          }
        } else {
          const int rr = R - SKP;
          float4 bb = *(const float4*)&rsb[rr];
          if (PRE) {
            hfu* pb = &outb[((size_t)b * ROWS + PADF + t) * CCH + rr];
            uint2 old = *(uint2*)pb;
            const _Float16* hp = (const _Float16*)&old;
            float v0 = (float)hp[0] + acc[mr][nr][0] + bb.x;
            float v1 = (float)hp[1] + acc[mr][nr][1] + bb.y;
            float v2 = (float)hp[2] + acc[mr][nr][2] + bb.z;
            float v3 = (float)hp[3] + acc[mr][nr][3] + bb.w;
            *(uint2*)pb = make_uint2(pk2(v0, v1), pk2(v2, v3));
          } else {
            float4* p = (float4*)&outf[((size_t)b * ROWS + PADF + t) * CCH + rr];
            float4 v = *p;
            v.x += acc[mr][nr][0] + bb.x;
            v.y += acc[mr][nr][1] + bb.y;
            v.z += acc[mr][nr][2] + bb.z;
            v.w += acc[mr][nr][3] + bb.w;
            *p = v;
          }
        }
      }
    }
  }
}

// ---------------- post1: y1 = relu(W1 @ relu(skip) + b1) -> fp16 ----------------
template <int PRE>
__global__ __launch_bounds__(256, 2) void post1_kernel(const float* __restrict__ skip,
                                                       const hfu* __restrict__ skiph,
                                                       const hfu* __restrict__ w,
                                                       const float* __restrict__ bias,
                                                       hfu* __restrict__ y1) {
  __shared__ uint4 sm[2048];
  uint4* sA = sm;
  uint4* sB = sm + 1024;
  const int tid = threadIdx.x;
  const int lane = tid & 63, wid = tid >> 6;
  const int wm = wid >> 1, wn = wid & 1;
  const int lr = lane & 15, lq = lane >> 4;
  const int t0 = blockIdx.x * 128;
  const int r0 = blockIdx.y * 128;
  const int b = blockIdx.z;
  f32x4 acc[4][4] = {};
  for (int kt = 0; kt < 4; ++kt) {  // K=256
#pragma unroll
    for (int c = 0; c < 4; ++c) {
      const int cb = c * 256 + wid * 64;
      const int ch = cb + lane;
      const int ksub = ch >> 7, mn = ch & 127;
      const int k0 = kt * 64 + ksub * 8;
      GLOAD16(w + (size_t)(r0 + mn) * SKP + k0, &sA[cb]);
      int row = t0 + mn;
      if (row > T_LEN - 1) row = T_LEN - 1;
      if (PRE) {
        uint4 u = *(const uint4*)&skiph[((size_t)b * T_LEN + row) * SKP + k0];
        const _Float16* hp = (const _Float16*)&u;
        float v[8];
#pragma unroll
        for (int j = 0; j < 8; ++j) v[j] = fmaxf((float)hp[j], 0.f);
        sB[ch] = pk8(v);
      } else {
        const float* src = skip + ((size_t)b * T_LEN + row) * SKP + k0;
        float4 f0 = *(const float4*)&src[0];
        float4 f1 = *(const float4*)&src[4];
        float v[8] = {fmaxf(f0.x, 0.f), fmaxf(f0.y, 0.f), fmaxf(f0.z, 0.f), fmaxf(f0.w, 0.f),
                      fmaxf(f1.x, 0.f), fmaxf(f1.y, 0.f), fmaxf(f1.z, 0.f), fmaxf(f1.w, 0.f)};
        sB[ch] = pk8(v);
      }
    }
    __syncthreads();
#pragma unroll
    for (int ks = 0; ks < 2; ++ks) {
      const int kb = (ks * 4 + lq) * 128;
      half8 av[4], bv[4];
#pragma unroll
      for (int r = 0; r < 4; ++r) {
        av[r] = *(const half8*)&sA[kb + wm * 64 + r * 16 + lr];
        bv[r] = *(const half8*)&sB[kb + wn * 64 + r * 16 + lr];
      }
#pragma unroll
      for (int mr = 0; mr < 4; ++mr)
#pragma unroll
        for (int nr = 0; nr < 4; ++nr)
          acc[mr][nr] = __builtin_amdgcn_mfma_f32_16x16x32_f16(av[mr], bv[nr], acc[mr][nr], 0, 0, 0);
    }
    __syncthreads();
  }
#pragma unroll
  for (int mr = 0; mr < 4; ++mr) {
    const int ob = r0 + wm * 64 + mr * 16 + lq * 4;
    float4 bb = *(const float4*)&bias[ob];
    const float bs[4] = {bb.x, bb.y, bb.z, bb.w};
#pragma unroll
    for (int nr = 0; nr < 4; ++nr) {
      const int t = t0 + wn * 64 + nr * 16 + lr;
      float v[4];
#pragma unroll
      for (int j = 0; j < 4; ++j) v[j] = fmaxf(acc[mr][nr][j] + bs[j], 0.f);
      *(uint2*)&y1[((size_t)b * HROWS + t) * SKP + ob] = make_uint2(pk2(v[0], v[1]), pk2(v[2], v[3]));
    }
  }
}

// ---------------- post2: out = W2 @ y1 + b2 -> d_out [b][t][q] fp32 ----------------
__global__ __launch_bounds__(256, 2) void post2_kernel(const hfu* __restrict__ y1,
                                                       const hfu* __restrict__ w,
                                                       const float* __restrict__ bias,
                                                       float* __restrict__ outp) {
  __shared__ uint4 sm[2048];
  uint4* sA = sm;
  uint4* sB = sm + 1024;
  const int tid = threadIdx.x;
  const int lane = tid & 63, wid = tid >> 6;
  const int wm = wid >> 1, wn = wid & 1;
  const int lr = lane & 15, lq = lane >> 4;
  const int t0 = blockIdx.x * 128;
  const int r0 = blockIdx.y * 128;
  const int b = blockIdx.z;
  f32x4 acc[4][4] = {};
  for (int kt = 0; kt < 4; ++kt) {
#pragma unroll
    for (int c = 0; c < 4; ++c) {
      const int cb = c * 256 + wid * 64;
      const int ch = cb + lane;
      const int ksub = ch >> 7, mn = ch & 127;
      const int k0 = kt * 64 + ksub * 8;
      GLOAD16(w + (size_t)(r0 + mn) * SKP + k0, &sA[cb]);
      GLOAD16(y1 + ((size_t)b * HROWS + t0 + mn) * SKP + k0, &sB[cb]);
    }
    __syncthreads();
#pragma unroll
    for (int ks = 0; ks < 2; ++ks) {
      const int kb = (ks * 4 + lq) * 128;
      half8 av[4], bv[4];
#pragma unroll
      for (int r = 0; r < 4; ++r) {
        av[r] = *(const half8*)&sA[kb + wm * 64 + r * 16 + lr];
        bv[r] = *(const half8*)&sB[kb + wn * 64 + r * 16 + lr];
      }
#pragma unroll
      for (int mr = 0; mr < 4; ++mr)
#pragma unroll
        for (int nr = 0; nr < 4; ++nr)
          acc[mr][nr] = __builtin_amdgcn_mfma_f32_16x16x32_f16(av[mr], bv[nr], acc[mr][nr], 0, 0, 0);
    }
    __syncthreads();
  }
#pragma unroll
  for (int mr = 0; mr < 4; ++mr) {
    const int ob = r0 + wm * 64 + mr * 16 + lq * 4;
    float4 bb = *(const float4*)&bias[ob];
#pragma unroll
    for (int nr = 0; nr < 4; ++nr) {
      const int t = t0 + wn * 64 + nr * 16 + lr;
      if (t < T_LEN) {
        float4 v;
        v.x = acc[mr][nr][0] + bb.x;
        v.y = acc[mr][nr][1] + bb.y;
        v.z = acc[mr][nr][2] + bb.z;
        v.w = acc[mr][nr][3] + bb.w;
        *(float4*)&outp[((size_t)b * T_LEN + t) * NQ + ob] = v;
      }
    }
  }
}

extern "C" void kernel_launch(void* const* d_in, const int* in_sizes, int n_in,
                              void* d_out, int out_size, void* d_ws, size_t ws_size,
                              hipStream_t stream) {
  const int* x = (const int*)d_in[0];
  const float* h = (const float*)d_in[1];
  const float* causal_w = (const float*)d_in[2];
  const float* causal_b = (const float*)d_in[3];
  const float* dil_sig_w = (const float*)d_in[4];
  const float* dil_sig_b = (const float*)d_in[5];
  const float* dil_tanh_w = (const float*)d_in[6];
  const float* dil_tanh_b = (const float*)d_in[7];
  const float* aux_sig_w = (const float*)d_in[8];
  const float* aux_sig_b = (const float*)d_in[9];
  const float* aux_tanh_w = (const float*)d_in[10];
  const float* aux_tanh_b = (const float*)d_in[11];
  const float* skip_w = (const float*)d_in[12];
  const float* skip_b = (const float*)d_in[13];
  const float* res_w = (const float*)d_in[14];
  const float* res_b = (const float*)d_in[15];
  const float* post1_w = (const float*)d_in[16];
  const float* post1_b = (const float*)d_in[17];
  const float* post2_w = (const float*)d_in[18];
  const float* post2_b = (const float*)d_in[19];
  float* outp = (float*)d_out;

  // allow 128KB dynamic LDS for gate (idempotent host-side attribute set)
  hipFuncSetAttribute((const void*)gate_kernel<1>,
                      hipFuncAttributeMaxDynamicSharedMemorySize, 131072);
  hipFuncSetAttribute((const void*)gate_kernel<0>,
                      hipFuncAttributeMaxDynamicSharedMemorySize, 131072);

  char* p = (char*)d_ws;
  auto alloc = [&](size_t bytes) {
    char* r = p;
    p += (bytes + 255) & ~(size_t)255;
    return r;
  };
  float* outf = (float*)alloc((size_t)BATCH * ROWS * CCH * 4);   // fp32 residual (PRE=0)
  float* skip = (float*)alloc((size_t)BATCH * T_LEN * SKP * 4);  // fp32 skip (PRE=0)
  hfu* zb = (hfu*)alloc((size_t)BATCH * HROWS * CCH * 2);        // z fp16 (reused as y1)
  hfu* hbf = (hfu*)alloc((size_t)BATCH * HROWS * AUXP * 2);
  hfu* auxsb = (hfu*)alloc((size_t)NLAYER * CCH * AUXP * 2);
  hfu* auxtb = (hfu*)alloc((size_t)NLAYER * CCH * AUXP * 2);
  hfu* p1b = (hfu*)alloc((size_t)NQ * SKP * 2);
  hfu* p2b = (hfu*)alloc((size_t)NQ * SKP * 2);
  float* cwt = (float*)alloc((size_t)2 * NQ * CCH * 4);          // transposed causal_w
  hfu* skiph = (hfu*)alloc((size_t)BATCH * T_LEN * SKP * 2);     // fp16 skip (PRE)
  hfu* y1 = zb;
  // optional (PRE) region
  hfu* outb = (hfu*)alloc((size_t)BATCH * ROWS * CCH * 2);       // fp16 residual (PRE)
  hfu* dilS = (hfu*)alloc((size_t)NLAYER * 2 * CCH * CCH * 2);
  hfu* dilT = (hfu*)alloc((size_t)NLAYER * 2 * CCH * CCH * 2);
  hfu* wsr = (hfu*)alloc((size_t)NLAYER * 768 * CCH * 2);
  const bool pre = ((size_t)(p - (char*)d_ws) <= ws_size);

  // weight conversions
  cvt_aux<<<256, 256, 0, stream>>>(aux_sig_w, auxsb);
  cvt_aux<<<256, 256, 0, stream>>>(aux_tanh_w, auxtb);
  cvt_copy<<<64, 256, 0, stream>>>(post1_w, p1b, NQ * SKP);
  cvt_copy<<<64, 256, 0, stream>>>(post2_w, p2b, NQ * SKP);
  cvt_cwt<<<1024, 256, 0, stream>>>(causal_w, cwt);
  if (pre) {
    cvt_dil2<<<4096, 256, 0, stream>>>(dil_sig_w, dil_tanh_w, dilS, dilT);
    cvt_skipres<<<2048, 256, 0, stream>>>(skip_w, res_w, wsr);
  }

  // zero: skip + padded rows of the residual master in use
  if (pre) {
    zero16<<<512, 256, 0, stream>>>((uint4*)skiph, (int)((size_t)BATCH * T_LEN * SKP * 2 / 16));
    for (int b = 0; b < BATCH; ++b) {
      zero16<<<32, 256, 0, stream>>>((uint4*)(outb + (size_t)b * ROWS * CCH), PADF * CCH * 2 / 16);
      zero16<<<48, 256, 0, stream>>>((uint4*)(outb + ((size_t)b * ROWS + PADF + T_LEN) * CCH),
                                     (TPAD - T_LEN) * CCH * 2 / 16);
    }
  } else {
    zero16<<<512, 256, 0, stream>>>((uint4*)skip, (int)((size_t)BATCH * T_LEN * SKP * 4 / 16));
    for (int b = 0; b < BATCH; ++b) {
      zero16<<<64, 256, 0, stream>>>((uint4*)(outf + (size_t)b * ROWS * CCH), PADF * CCH * 4 / 16);
      zero16<<<96, 256, 0, stream>>>((uint4*)(outf + ((size_t)b * ROWS + PADF + T_LEN) * CCH),
                                     (TPAD - T_LEN) * CCH * 4 / 16);
    }
  }

  htrans_kernel<<<dim3(128, 2), 256, 0, stream>>>(h, hbf);
  if (pre)
    embed_kernel<1><<<dim3(2000, 2), 256, 0, stream>>>(x, cwt, causal_b, nullptr, outb);
  else
    embed_kernel<0><<<dim3(2000, 2), 256, 0, stream>>>(x, cwt, causal_b, outf, nullptr);

  for (int l = 0; l < NLAYER; ++l) {
    const int d = 1 << (l % 10);
    if (pre) {
      gate_kernel<1><<<256, 512, 131072, stream>>>(
          outb, nullptr, hbf, dilS + (size_t)l * 2 * CCH * CCH, dilT + (size_t)l * 2 * CCH * CCH,
          auxsb + (size_t)l * CCH * AUXP, auxtb + (size_t)l * CCH * AUXP,
          dil_sig_b + (size_t)l * CCH, aux_sig_b + (size_t)l * CCH,
          dil_tanh_b + (size_t)l * CCH, aux_tanh_b + (size_t)l * CCH, zb, d);
      update_kernel<1><<<768, 512, 0, stream>>>(
          zb, wsr + (size_t)l * 768 * CCH, nullptr, nullptr,
          skip_b + (size_t)l * SKP, res_b + (size_t)l * CCH, nullptr, skiph, nullptr, outb);
    } else {
      gate_kernel<0><<<256, 512, 131072, stream>>>(
          nullptr, outf, hbf, dil_sig_w + (size_t)l * CCH * CCH * 2,
          dil_tanh_w + (size_t)l * CCH * CCH * 2,
          auxsb + (size_t)l * CCH * AUXP, auxtb + (size_t)l * CCH * AUXP,
          dil_sig_b + (size_t)l * CCH, aux_sig_b + (size_t)l * CCH,
          dil_tanh_b + (size_t)l * CCH, aux_tanh_b + (size_t)l * CCH, zb, d);
      update_kernel<0><<<768, 512, 0, stream>>>(
          zb, nullptr, skip_w + (size_t)l * SKP * CCH, res_w + (size_t)l * CCH * CCH,
          skip_b + (size_t)l * SKP, res_b + (size_t)l * CCH, skip, nullptr, outf, nullptr);
    }
  }

  if (pre)
    post1_kernel<1><<<dim3(63, 2, BATCH), 256, 0, stream>>>(nullptr, skiph, p1b, post1_b, y1);
  else
    post1_kernel<0><<<dim3(63, 2, BATCH), 256, 0, stream>>>(skip, nullptr, p1b, post1_b, y1);
  post2_kernel<<<dim3(63, 2, BATCH), 256, 0, stream>>>(y1, p2b, post2_b, outp);
}

// Round 13
// 2026.167 us; speedup vs baseline: 1.0880x; 1.0302x over previous
//
#include <hip/hip_runtime.h>
#include <math.h>

#define T_LEN 8000
#define BATCH 2
#define CCH 512
#define SKP 256
#define AUXP 32
#define NQ 256
#define NLAYER 30
#define PADF 512
#define TPAD 8192
#define ROWS (PADF + TPAD)         // 8704 padded rows
#define HROWS TPAD                 // 8192 rows (z, h, y1)

typedef unsigned short hfu;        // fp16 as raw bits
typedef unsigned int u32;
typedef __attribute__((ext_vector_type(8))) _Float16 half8;
typedef __attribute__((ext_vector_type(4))) float f32x4;

#define GLOAD16(g, l)                                                          \
  __builtin_amdgcn_global_load_lds(                                            \
      (const __attribute__((address_space(1))) void*)(g),                      \
      (__attribute__((address_space(3))) void*)(l), 16, 0, 0)

__device__ inline hfu hfbits(float f) {
  union { _Float16 h; hfu u; } x;
  x.h = (_Float16)f;
  return x.u;
}
__device__ inline u32 pk2(float a, float b) {
  return (u32)hfbits(a) | ((u32)hfbits(b) << 16);
}
__device__ inline uint4 pk8(const float f[8]) {
  return make_uint4(pk2(f[0], f[1]), pk2(f[2], f[3]), pk2(f[4], f[5]), pk2(f[6], f[7]));
}
// pair-interleaved XOR LDS layout for BK=32 tiles (4 chunks/row), update kernel.
__device__ inline int ldsL(int row, int ck) {
  return ((row >> 1) << 3) + ((((ck) ^ ((row >> 1) & 3)) << 1) | (row & 1));
}

// ---------------- utility: zero / converts ----------------
__global__ __launch_bounds__(256) void zero16(uint4* p, int n) {
  for (int i = blockIdx.x * 256 + threadIdx.x; i < n; i += gridDim.x * 256)
    p[i] = make_uint4(0u, 0u, 0u, 0u);
}

// dil weights: [30][512][512][2] f32 -> [30][2][512][512] fp16.
// 64B-read / 2x16B-write per thread (coalesced both sides).
__global__ __launch_bounds__(256) void cvt_dil2b(const float* __restrict__ inS,
                                                 const float* __restrict__ inT,
                                                 hfu* __restrict__ outS, hfu* __restrict__ outT) {
  const long NG = (long)NLAYER * CCH * (CCH / 8);  // i8 granularity
  for (long g2 = (long)blockIdx.x * 256 + threadIdx.x; g2 < 2 * NG; g2 += (long)gridDim.x * 256) {
    const int sel = (int)(g2 >= NG);
    const long g = sel ? (g2 - NG) : g2;
    const float* in = sel ? inT : inS;
    hfu* out = sel ? outT : outS;
    const int i8 = (int)(g & 63) * 8;
    const int o = (int)((g >> 6) & 511);
    const int l = (int)(g >> 15);
    const float* pp = in + (((size_t)l * CCH + o) * CCH + i8) * 2;
    float4 a = *(const float4*)pp;
    float4 bq = *(const float4*)(pp + 4);
    float4 c = *(const float4*)(pp + 8);
    float4 e = *(const float4*)(pp + 12);
    const float t0[8] = {a.x, a.z, bq.x, bq.z, c.x, c.z, e.x, e.z};
    const float t1[8] = {a.y, a.w, bq.y, bq.w, c.y, c.w, e.y, e.w};
    hfu* ob = out + ((size_t)l * 2 * CCH + o) * CCH + i8;
    *(uint4*)ob = pk8(t0);
    *(uint4*)(ob + (size_t)CCH * CCH) = pk8(t1);
  }
}

// skip_w [30][256][512] + res_w [30][512][512] -> stacked [30][768][512] fp16
__global__ __launch_bounds__(256) void cvt_skipres(const float* __restrict__ skw,
                                                   const float* __restrict__ rsw,
                                                   hfu* __restrict__ out) {
  const long NG = (long)NLAYER * 768 * (CCH / 4);
  for (long g = (long)blockIdx.x * 256 + threadIdx.x; g < NG; g += (long)gridDim.x * 256) {
    const int i4 = (int)(g & 127) * 4;
    const int r = (int)((g >> 7) % 768);
    const int l = (int)(g / (128 * 768));
    const float* src = (r < SKP) ? (skw + ((size_t)l * SKP + r) * CCH + i4)
                                 : (rsw + ((size_t)l * CCH + (r - SKP)) * CCH + i4);
    float4 f = *(const float4*)src;
    *(uint2*)(out + ((size_t)l * 768 + r) * CCH + i4) = make_uint2(pk2(f.x, f.y), pk2(f.z, f.w));
  }
}

// aux weights [30][512][28] -> [30][512][32] fp16 zero-padded
__global__ __launch_bounds__(256) void cvt_aux(const float* __restrict__ in, hfu* __restrict__ out) {
  const int N = NLAYER * CCH * AUXP;
  for (int i = blockIdx.x * 256 + threadIdx.x; i < N; i += gridDim.x * 256) {
    const int j = i & 31;
    const int o = (i >> 5) & 511;
    const int l = i >> 14;
    float v = (j < 28) ? in[((size_t)l * CCH + o) * 28 + j] : 0.f;
    out[i] = hfbits(v);
  }
}

__global__ __launch_bounds__(256) void cvt_copy(const float* __restrict__ in, hfu* __restrict__ out, int n) {
  for (int i = blockIdx.x * 256 + threadIdx.x; i < n; i += gridDim.x * 256)
    out[i] = hfbits(in[i]);
}

// causal_w [512][256][2] f32 -> cwt [2][256][512] f32 (transposed for coalesced embed)
__global__ __launch_bounds__(256) void cvt_cwt(const float* __restrict__ cw, float* __restrict__ out) {
  const int N = 2 * NQ * CCH;
  for (int i = blockIdx.x * 256 + threadIdx.x; i < N; i += gridDim.x * 256) {
    const int tap = i >> 17;
    const int r = i & 131071;
    const int xq = r >> 9;
    const int o = r & 511;
    out[i] = cw[((size_t)o * NQ + xq) * 2 + tap];
  }
}

// h [b][28][8000] f32 -> [b][8192][32] fp16 zero-padded
__global__ __launch_bounds__(256) void htrans_kernel(const float* __restrict__ h, hfu* __restrict__ hbf) {
  const int b = blockIdx.y;
  const int t = blockIdx.x * 64 + (threadIdx.x & 63);
  const int j0 = threadIdx.x >> 6;
#pragma unroll
  for (int j = j0; j < AUXP; j += 4) {
    float v = (j < 28 && t < T_LEN) ? h[((size_t)b * 28 + j) * T_LEN + t] : 0.f;
    hbf[((size_t)b * HROWS + t) * AUXP + j] = hfbits(v);
  }
}

// ---------------- embed (coalesced via cwt) ----------------
template <int PRE>
__global__ __launch_bounds__(256) void embed_kernel(const int* __restrict__ x,
                                                    const float* __restrict__ cwt,
                                                    const float* __restrict__ cb,
                                                    float* __restrict__ outf,
                                                    hfu* __restrict__ outb) {
  const int b = blockIdx.y;
  const int t = blockIdx.x * 4 + (threadIdx.x >> 6);
  const int o = (threadIdx.x & 63) * 8;
  const int xc = x[(size_t)b * T_LEN + t] & 255;
  const int xp = (t > 0) ? (x[(size_t)b * T_LEN + t - 1] & 255) : 0;
  const float won = (t > 0) ? 1.f : 0.f;
  const float* c1 = cwt + 131072 + (size_t)xc * CCH + o;
  const float* c0 = cwt + (size_t)xp * CCH + o;
  float v[8];
#pragma unroll
  for (int j = 0; j < 8; ++j) v[j] = cb[o + j] + c1[j] + won * c0[j];
  if (PRE) {
    *(uint4*)&outb[((size_t)b * ROWS + PADF + t) * CCH + o] = pk8(v);
  } else {
    float* po = outf + ((size_t)b * ROWS + PADF + t) * CCH + o;
    *(float4*)po = make_float4(v[0], v[1], v[2], v[3]);
    *(float4*)(po + 4) = make_float4(v[4], v[5], v[6], v[7]);
  }
}

// ---------------- gate: sig/tanh dilated GEMMs + aux + gating ----------------
// BM=128, BN=256, BK=64, 17 K-steps, 512 threads (8 waves: wm2 x wn4, mr4 x nr4).
// Grid 256 = 1 block/CU. 2-phase x 64KB dynamic LDS. Pointer-hoisted staging,
// hoisted swizzled LDS offsets, SINGLE barrier per step, stage issued under MFMA.
template <int PRE>
__global__ __launch_bounds__(512, 2) void gate_kernel(
    const hfu* __restrict__ actb, const float* __restrict__ actf,
    const hfu* __restrict__ hbf,
    const void* __restrict__ wsp, const void* __restrict__ wtp,
    const hfu* __restrict__ auxs, const hfu* __restrict__ auxt,
    const float* __restrict__ bs1, const float* __restrict__ bs2,
    const float* __restrict__ bt1, const float* __restrict__ bt2,
    hfu* __restrict__ z, int d) {
  extern __shared__ uint4 smd[];  // 2 phases x {As 1024, At 1024, B 2048} uint4
  const int tid = threadIdx.x;
  const int lane = tid & 63, wid = tid >> 6;
  const int wm = wid >> 2, wn = wid & 3;
  const int lr = lane & 15, lq = lane >> 4;

  const int n = blockIdx.x;               // 256 = 8 xcd * 32
  const int f = (n & 7) * 32 + (n >> 3);
  const int tt = f >> 3, inner = f & 7;   // 32 t-tiles x (4 og x 2 b)
  const int o0 = (inner >> 1) * 128;
  const int b = inner & 1;
  const int t0 = tt * 256;

  f32x4 accS[4][4] = {};
  f32x4 accT[4][4] = {};

  if (PRE) {
    // ---- hoisted per-thread staging pointers (tau=1, koff=0 start) ----
    const int sw0 = tid, sw1 = 512 + tid;
    const int rw0 = sw0 >> 3, cw0 = (sw0 & 7) ^ (rw0 & 7);
    const int rw1 = sw1 >> 3, cw1 = (sw1 & 7) ^ (rw1 & 7);
    const hfu* wsP0 = (const hfu*)wsp + ((size_t)CCH + o0 + rw0) * CCH + cw0 * 8;
    const hfu* wsP1 = (const hfu*)wsp + ((size_t)CCH + o0 + rw1) * CCH + cw1 * 8;
    const hfu* wtP0 = (const hfu*)wtp + ((size_t)CCH + o0 + rw0) * CCH + cw0 * 8;
    const hfu* wtP1 = (const hfu*)wtp + ((size_t)CCH + o0 + rw1) * CCH + cw1 * 8;
    const hfu *a1P0, *a1P1, *a1P2, *a1P3, *a0P0, *a0P1, *a0P2, *a0P3;
    {
      const int s0 = tid, s1 = 512 + tid, s2 = 1024 + tid, s3 = 1536 + tid;
      const int r0_ = s0 >> 3, c0_ = (s0 & 7) ^ (r0_ & 7);
      const int r1_ = s1 >> 3, c1_ = (s1 & 7) ^ (r1_ & 7);
      const int r2_ = s2 >> 3, c2_ = (s2 & 7) ^ (r2_ & 7);
      const int r3_ = s3 >> 3, c3_ = (s3 & 7) ^ (r3_ & 7);
      const hfu* base1 = actb + ((size_t)b * ROWS + PADF + t0) * CCH;
      a1P0 = base1 + (size_t)r0_ * CCH + c0_ * 8;
      a1P1 = base1 + (size_t)r1_ * CCH + c1_ * 8;
      a1P2 = base1 + (size_t)r2_ * CCH + c2_ * 8;
      a1P3 = base1 + (size_t)r3_ * CCH + c3_ * 8;
      const hfu* base0 = actb + ((size_t)b * ROWS + PADF + t0 - d) * CCH;
      a0P0 = base0 + (size_t)r0_ * CCH + c0_ * 8;
      a0P1 = base0 + (size_t)r1_ * CCH + c1_ * 8;
      a0P2 = base0 + (size_t)r2_ * CCH + c2_ * 8;
      a0P3 = base0 + (size_t)r3_ * CCH + c3_ * 8;
    }
    // ---- hoisted fragment LDS offsets (uint4 index within plane) ----
    int offA[2][4], offB[2][4];
#pragma unroll
    for (int kk = 0; kk < 2; ++kk) {
#pragma unroll
      for (int mr = 0; mr < 4; ++mr) {
        const int row = wm * 64 + mr * 16 + lr;
        offA[kk][mr] = row * 8 + ((kk * 4 + lq) ^ (row & 7));
      }
#pragma unroll
      for (int nr = 0; nr < 4; ++nr) {
        const int row = wn * 64 + nr * 16 + lr;
        offB[kk][nr] = row * 8 + ((kk * 4 + lq) ^ (row & 7));
      }
    }

    auto issue_stage = [&](int ihs) {
      uint4* dst = smd + ((ihs & 1) << 12);
      if (ihs < 16) {
        GLOAD16(wsP0, &dst[tid]);
        GLOAD16(wsP1, &dst[512 + tid]);
        GLOAD16(wtP0, &dst[1024 + tid]);
        GLOAD16(wtP1, &dst[1536 + tid]);
        if (ihs < 8) {
          GLOAD16(a1P0, &dst[2048 + tid]);
          GLOAD16(a1P1, &dst[2560 + tid]);
          GLOAD16(a1P2, &dst[3072 + tid]);
          GLOAD16(a1P3, &dst[3584 + tid]);
          a1P0 += 64; a1P1 += 64; a1P2 += 64; a1P3 += 64;
        } else {
          GLOAD16(a0P0, &dst[2048 + tid]);
          GLOAD16(a0P1, &dst[2560 + tid]);
          GLOAD16(a0P2, &dst[3072 + tid]);
          GLOAD16(a0P3, &dst[3584 + tid]);
          a0P0 += 64; a0P1 += 64; a0P2 += 64; a0P3 += 64;
        }
        if (ihs == 7) {
          wsP0 -= 262592; wsP1 -= 262592; wtP0 -= 262592; wtP1 -= 262592;
        } else {
          wsP0 += 64; wsP1 += 64; wtP0 += 64; wtP1 += 64;
        }
      } else {  // aux (K=32, 4 chunks/row, swizzle ck^(row&3)) -> phase 0
        {
          const int row = tid >> 2, ck = (tid & 3) ^ (row & 3);
          GLOAD16(auxs + (size_t)(o0 + row) * AUXP + ck * 8, &dst[tid]);
          GLOAD16(auxt + (size_t)(o0 + row) * AUXP + ck * 8, &dst[1024 + tid]);
        }
#pragma unroll
        for (int c = 0; c < 2; ++c) {
          const int s = c * 512 + tid;
          const int row = s >> 2, ck = (s & 3) ^ (row & 3);
          GLOAD16(hbf + ((size_t)b * HROWS + t0 + row) * AUXP + ck * 8, &dst[2048 + s]);
        }
      }
    };

    issue_stage(0);
    for (int ih = 0; ih < 17; ++ih) {
      asm volatile("s_waitcnt vmcnt(0)" ::: "memory");
      __builtin_amdgcn_s_barrier();
      __builtin_amdgcn_sched_barrier(0);
      const uint4* base = smd + ((ih & 1) << 12);
      if (ih < 16) {
        half8 af[4], ag[4], bv[4];
        // kk0 fragment reads
#pragma unroll
        for (int mr = 0; mr < 4; ++mr) {
          af[mr] = *(const half8*)&base[offA[0][mr]];
          ag[mr] = *(const half8*)&base[1024 + offA[0][mr]];
        }
#pragma unroll
        for (int nr = 0; nr < 4; ++nr) bv[nr] = *(const half8*)&base[2048 + offB[0][nr]];
        // next-step stage issue overlaps the MFMA cluster below
        issue_stage(ih + 1);
        __builtin_amdgcn_s_setprio(1);
#pragma unroll
        for (int mr = 0; mr < 4; ++mr)
#pragma unroll
          for (int nr = 0; nr < 4; ++nr) {
            accS[mr][nr] = __builtin_amdgcn_mfma_f32_16x16x32_f16(af[mr], bv[nr], accS[mr][nr], 0, 0, 0);
            accT[mr][nr] = __builtin_amdgcn_mfma_f32_16x16x32_f16(ag[mr], bv[nr], accT[mr][nr], 0, 0, 0);
          }
        // kk1
#pragma unroll
        for (int mr = 0; mr < 4; ++mr) {
          af[mr] = *(const half8*)&base[offA[1][mr]];
          ag[mr] = *(const half8*)&base[1024 + offA[1][mr]];
        }
#pragma unroll
        for (int nr = 0; nr < 4; ++nr) bv[nr] = *(const half8*)&base[2048 + offB[1][nr]];
#pragma unroll
        for (int mr = 0; mr < 4; ++mr)
#pragma unroll
          for (int nr = 0; nr < 4; ++nr) {
            accS[mr][nr] = __builtin_amdgcn_mfma_f32_16x16x32_f16(af[mr], bv[nr], accS[mr][nr], 0, 0, 0);
            accT[mr][nr] = __builtin_amdgcn_mfma_f32_16x16x32_f16(ag[mr], bv[nr], accT[mr][nr], 0, 0, 0);
          }
        __builtin_amdgcn_s_setprio(0);
        __builtin_amdgcn_sched_barrier(0);
      } else {
        // aux compute (phase 0, 4-chunk layout)
        half8 af[4], ag[4], bv[4];
#pragma unroll
        for (int mr = 0; mr < 4; ++mr) {
          const int row = wm * 64 + mr * 16 + lr;
          const int idx = row * 4 + (lq ^ (row & 3));
          af[mr] = *(const half8*)&base[idx];
          ag[mr] = *(const half8*)&base[1024 + idx];
        }
#pragma unroll
        for (int nr = 0; nr < 4; ++nr) {
          const int row = wn * 64 + nr * 16 + lr;
          bv[nr] = *(const half8*)&base[2048 + row * 4 + (lq ^ (row & 3))];
        }
#pragma unroll
        for (int mr = 0; mr < 4; ++mr)
#pragma unroll
          for (int nr = 0; nr < 4; ++nr) {
            accS[mr][nr] = __builtin_amdgcn_mfma_f32_16x16x32_f16(af[mr], bv[nr], accS[mr][nr], 0, 0, 0);
            accT[mr][nr] = __builtin_amdgcn_mfma_f32_16x16x32_f16(ag[mr], bv[nr], accT[mr][nr], 0, 0, 0);
          }
      }
    }
  } else {
    // fallback fp32-source path (2-barrier, recompute addresses) — correctness only
    auto stage_dil = [&](int ih, int p) {
      const int base = p * 4096;
      const int tau = (ih < 8) ? 1 : 0;
      const int koff = (ih & 7) * 64;
      const float* wsf = (const float*)wsp;
      const float* wtf = (const float*)wtp;
#pragma unroll
      for (int c = 0; c < 2; ++c) {
        const int s = c * 512 + tid;
        const int row = s >> 3, ck = (s & 7) ^ (row & 7);
        const size_t fb = ((size_t)(o0 + row) * CCH + koff + ck * 8) * 2;
        float vs[8], vt[8];
#pragma unroll
        for (int j = 0; j < 4; ++j) {
          float4 fs = *(const float4*)&wsf[fb + j * 4];
          float4 ft = *(const float4*)&wtf[fb + j * 4];
          vs[2 * j] = tau ? fs.y : fs.x;
          vs[2 * j + 1] = tau ? fs.w : fs.z;
          vt[2 * j] = tau ? ft.y : ft.x;
          vt[2 * j + 1] = tau ? ft.w : ft.z;
        }
        smd[base + s] = pk8(vs);
        smd[base + 1024 + s] = pk8(vt);
      }
#pragma unroll
      for (int c = 0; c < 4; ++c) {
        const int s = c * 512 + tid;
        const int row = s >> 3, ck = (s & 7) ^ (row & 7);
        const float* ar = actf + ((size_t)b * ROWS + PADF + t0 + row - (tau ? 0 : d)) * CCH + koff + ck * 8;
        float4 f0 = *(const float4*)&ar[0];
        float4 f1 = *(const float4*)&ar[4];
        float vb[8] = {f0.x, f0.y, f0.z, f0.w, f1.x, f1.y, f1.z, f1.w};
        smd[base + 2048 + s] = pk8(vb);
      }
    };
    auto stage_aux0 = [&](int p) {
      const int base = p * 4096;
      {
        const int row = tid >> 2, ck = (tid & 3) ^ (row & 3);
        smd[base + tid] = *(const uint4*)&auxs[(size_t)(o0 + row) * AUXP + ck * 8];
        smd[base + 1024 + tid] = *(const uint4*)&auxt[(size_t)(o0 + row) * AUXP + ck * 8];
      }
#pragma unroll
      for (int c = 0; c < 2; ++c) {
        const int s = c * 512 + tid;
        const int row = s >> 2, ck = (s & 3) ^ (row & 3);
        smd[base + 2048 + s] = *(const uint4*)&hbf[((size_t)b * HROWS + t0 + row) * AUXP + ck * 8];
      }
    };
    for (int ih = 0; ih < 17; ++ih) {
      if (ih < 16) stage_dil(ih, ih & 1); else stage_aux0(0);
      __syncthreads();
      const uint4* base = smd + ((ih & 1) << 12);
      if (ih < 16) {
#pragma unroll
        for (int kk = 0; kk < 2; ++kk) {
          half8 af[4], ag[4], bv[4];
#pragma unroll
          for (int mr = 0; mr < 4; ++mr) {
            const int row = wm * 64 + mr * 16 + lr;
            const int idx = row * 8 + ((kk * 4 + lq) ^ (row & 7));
            af[mr] = *(const half8*)&base[idx];
            ag[mr] = *(const half8*)&base[1024 + idx];
          }
#pragma unroll
          for (int nr = 0; nr < 4; ++nr) {
            const int row = wn * 64 + nr * 16 + lr;
            bv[nr] = *(const half8*)&base[2048 + row * 8 + ((kk * 4 + lq) ^ (row & 7))];
          }
#pragma unroll
          for (int mr = 0; mr < 4; ++mr)
#pragma unroll
            for (int nr = 0; nr < 4; ++nr) {
              accS[mr][nr] = __builtin_amdgcn_mfma_f32_16x16x32_f16(af[mr], bv[nr], accS[mr][nr], 0, 0, 0);
              accT[mr][nr] = __builtin_amdgcn_mfma_f32_16x16x32_f16(ag[mr], bv[nr], accT[mr][nr], 0, 0, 0);
            }
        }
      } else {
        half8 af[4], ag[4], bv[4];
#pragma unroll
        for (int mr = 0; mr < 4; ++mr) {
          const int row = wm * 64 + mr * 16 + lr;
          const int idx = row * 4 + (lq ^ (row & 3));
          af[mr] = *(const half8*)&base[idx];
          ag[mr] = *(const half8*)&base[1024 + idx];
        }
#pragma unroll
        for (int nr = 0; nr < 4; ++nr) {
          const int row = wn * 64 + nr * 16 + lr;
          bv[nr] = *(const half8*)&base[2048 + row * 4 + (lq ^ (row & 3))];
        }
#pragma unroll
        for (int mr = 0; mr < 4; ++mr)
#pragma unroll
          for (int nr = 0; nr < 4; ++nr) {
            accS[mr][nr] = __builtin_amdgcn_mfma_f32_16x16x32_f16(af[mr], bv[nr], accS[mr][nr], 0, 0, 0);
            accT[mr][nr] = __builtin_amdgcn_mfma_f32_16x16x32_f16(ag[mr], bv[nr], accT[mr][nr], 0, 0, 0);
          }
      }
      __syncthreads();
    }
  }

  // epilogue: bias + sigmoid*tanh -> z fp16 [b][t][ch]
#pragma unroll
  for (int mr = 0; mr < 4; ++mr) {
    const int ob = o0 + wm * 64 + mr * 16 + lq * 4;
    float4 x1 = *(const float4*)&bs1[ob];
    float4 x2 = *(const float4*)&bs2[ob];
    float4 y1 = *(const float4*)&bt1[ob];
    float4 y2 = *(const float4*)&bt2[ob];
    const float sb[4] = {x1.x + x2.x, x1.y + x2.y, x1.z + x2.z, x1.w + x2.w};
    const float tb[4] = {y1.x + y2.x, y1.y + y2.y, y1.z + y2.z, y1.w + y2.w};
#pragma unroll
    for (int nr = 0; nr < 4; ++nr) {
      const int t = t0 + wn * 64 + nr * 16 + lr;
      float zv[4];
#pragma unroll
      for (int j = 0; j < 4; ++j) {
        float sv = accS[mr][nr][j] + sb[j];
        float tv = accT[mr][nr][j] + tb[j];
        float sg = __builtin_amdgcn_rcpf(1.f + __expf(-sv));
        float e2 = __expf(2.f * tv);
        float th = 1.f - 2.f * __builtin_amdgcn_rcpf(e2 + 1.f);
        zv[j] = sg * th;
      }
      *(uint2*)&z[((size_t)b * HROWS + t) * CCH + ob] = make_uint2(pk2(zv[0], zv[1]), pk2(zv[2], zv[3]));
    }
  }
}

// ---------------- update: [skip_w; res_w] @ z, RMW skip/residual ----------------
// BM=128, BN=128, BK=32, 512 threads, grid 768 (xcd owns tt [xcd*8,...)).
// 2-phase 32KB LDS, SINGLE barrier per step, pointer-hoisted staging.
template <int PRE>
__global__ __launch_bounds__(512, 4) void update_kernel(
    const hfu* __restrict__ z, const void* __restrict__ wp,
    const float* __restrict__ skwf, const float* __restrict__ rswf,
    const float* __restrict__ skb, const float* __restrict__ rsb,
    float* __restrict__ skip, hfu* __restrict__ skiph,
    float* __restrict__ outf, hfu* __restrict__ outb) {
  __shared__ uint4 sm[2048];  // 32KB: 2 phases x {A 512, B 512}
  const int tid = threadIdx.x;
  const int lane = tid & 63, wid = tid >> 6;
  const int wm = wid >> 1, wn = wid & 1;
  const int lr = lane & 15, lq = lane >> 4;

  const int n = blockIdx.x;                // 768 = 8 xcd * 96
  const int xcd = n & 7, j = n >> 3;       // j 0..95
  const int ttl = j / 12, inner = j % 12;  // 8 local t-tiles x (6 rg x 2 b)
  const int tt = xcd * 8 + ttl;
  if (tt > 62) return;                     // 63 t-tiles; xcd7 idles 12 blocks
  const int rg = inner >> 1, b = inner & 1;
  const int r0 = rg * 128;                 // 0..640
  const int t0 = tt * 128;

  f32x4 acc[2][4] = {};
  const int pr = tid >> 3, w = tid & 7;
  const int row = (pr << 1) | (w & 1);      // 0..127
  const int ck = (w >> 1) ^ (pr & 3);

  if (PRE) {
    const hfu* wPtr = (const hfu*)wp + (size_t)(r0 + row) * CCH + ck * 8;
    const hfu* zPtr = z + ((size_t)b * HROWS + t0 + row) * CCH + ck * 8;
    // hoisted fragment offsets
    int offa[2], offb[4];
#pragma unroll
    for (int mr = 0; mr < 2; ++mr) offa[mr] = ldsL(wm * 32 + mr * 16 + lr, lq);
#pragma unroll
    for (int nr = 0; nr < 4; ++nr) offb[nr] = ldsL(wn * 64 + nr * 16 + lr, lq);

    GLOAD16(wPtr, &sm[tid]);
    GLOAD16(zPtr, &sm[512 + tid]);
    wPtr += 32; zPtr += 32;
    for (int ih = 0; ih < 16; ++ih) {
      asm volatile("s_waitcnt vmcnt(0)" ::: "memory");
      __builtin_amdgcn_s_barrier();
      __builtin_amdgcn_sched_barrier(0);
      const uint4* base = sm + ((ih & 1) << 10);
      half8 av[2], bv[4];
#pragma unroll
      for (int mr = 0; mr < 2; ++mr) av[mr] = *(const half8*)&base[offa[mr]];
#pragma unroll
      for (int nr = 0; nr < 4; ++nr) bv[nr] = *(const half8*)&base[512 + offb[nr]];
      if (ih < 15) {
        uint4* dst = sm + (((ih + 1) & 1) << 10);
        GLOAD16(wPtr, &dst[tid]);
        GLOAD16(zPtr, &dst[512 + tid]);
        wPtr += 32; zPtr += 32;
      }
      __builtin_amdgcn_s_setprio(1);
#pragma unroll
      for (int mr = 0; mr < 2; ++mr)
#pragma unroll
        for (int nr = 0; nr < 4; ++nr)
          acc[mr][nr] = __builtin_amdgcn_mfma_f32_16x16x32_f16(av[mr], bv[nr], acc[mr][nr], 0, 0, 0);
      __builtin_amdgcn_s_setprio(0);
      __builtin_amdgcn_sched_barrier(0);
    }
  } else {
    for (int ih = 0; ih < 16; ++ih) {
      const int base = (ih & 1) * 1024;
      const int k0 = ih * 32;
      const int R = r0 + row;
      const float* src = (R < SKP) ? (skwf + (size_t)R * CCH + k0 + ck * 8)
                                   : (rswf + (size_t)(R - SKP) * CCH + k0 + ck * 8);
      float4 f0 = *(const float4*)&src[0];
      float4 f1 = *(const float4*)&src[4];
      float v[8] = {f0.x, f0.y, f0.z, f0.w, f1.x, f1.y, f1.z, f1.w};
      sm[base + tid] = pk8(v);
      sm[base + 512 + tid] = *(const uint4*)&z[((size_t)b * HROWS + t0 + row) * CCH + k0 + ck * 8];
      __syncthreads();
      half8 av[2], bv[4];
#pragma unroll
      for (int mr = 0; mr < 2; ++mr) av[mr] = *(const half8*)&sm[base + ldsL(wm * 32 + mr * 16 + lr, lq)];
#pragma unroll
      for (int nr = 0; nr < 4; ++nr) bv[nr] = *(const half8*)&sm[base + 512 + ldsL(wn * 64 + nr * 16 + lr, lq)];
#pragma unroll
      for (int mr = 0; mr < 2; ++mr)
#pragma unroll
        for (int nr = 0; nr < 4; ++nr)
          acc[mr][nr] = __builtin_amdgcn_mfma_f32_16x16x32_f16(av[mr], bv[nr], acc[mr][nr], 0, 0, 0);
      __syncthreads();
    }
  }

  const bool iskip = (r0 < SKP);
#pragma unroll
  for (int mr = 0; mr < 2; ++mr) {
    const int R = r0 + wm * 32 + mr * 16 + lq * 4;
#pragma unroll
    for (int nr = 0; nr < 4; ++nr) {
      const int t = t0 + wn * 64 + nr * 16 + lr;
      if (t < T_LEN) {
        if (iskip) {
          float4 bb = *(const float4*)&skb[R];
          if (PRE) {
            hfu* ps = &skiph[((size_t)b * T_LEN + t) * SKP + R];
            uint2 old = *(uint2*)ps;
            const _Float16* hp = (const _Float16*)&old;
            float v0 = (float)hp[0] + acc[mr][nr][0] + bb.x;
            float v1 = (float)hp[1] + acc[mr][nr][1] + bb.y;
            float v2 = (float)hp[2] + acc[mr][nr][2] + bb.z;
            float v3 = (float)hp[3] + acc[mr][nr][3] + bb.w;
            *(uint2*)ps = make_uint2(pk2(v0, v1), pk2(v2, v3));
          } else {
            float4* p = (float4*)&skip[((size_t)b * T_LEN + t) * SKP + R];
            float4 v = *p;
            v.x += acc[mr][nr][0] + bb.x;
            v.y += acc[mr][nr][1] + bb.y;
            v.z += acc[mr][nr][2] + bb.z;
            v.w += acc[mr][nr][3] + bb.w;
            *p = v;
          }
        } else {
          const int rr = R - SKP;
          float4 bb = *(const float4*)&rsb[rr];
          if (PRE) {
            hfu* pb = &outb[((size_t)b * ROWS + PADF + t) * CCH + rr];
            uint2 old = *(uint2*)pb;
            const _Float16* hp = (const _Float16*)&old;
            float v0 = (float)hp[0] + acc[mr][nr][0] + bb.x;
            float v1 = (float)hp[1] + acc[mr][nr][1] + bb.y;
            float v2 = (float)hp[2] + acc[mr][nr][2] + bb.z;
            float v3 = (float)hp[3] + acc[mr][nr][3] + bb.w;
            *(uint2*)pb = make_uint2(pk2(v0, v1), pk2(v2, v3));
          } else {
            float4* p = (float4*)&outf[((size_t)b * ROWS + PADF + t) * CCH + rr];
            float4 v = *p;
            v.x += acc[mr][nr][0] + bb.x;
            v.y += acc[mr][nr][1] + bb.y;
            v.z += acc[mr][nr][2] + bb.z;
            v.w += acc[mr][nr][3] + bb.w;
            *p = v;
          }
        }
      }
    }
  }
}

// ---------------- post1: y1 = relu(W1 @ relu(skip) + b1) -> fp16 ----------------
template <int PRE>
__global__ __launch_bounds__(256, 2) void post1_kernel(const float* __restrict__ skip,
                                                       const hfu* __restrict__ skiph,
                                                       const hfu* __restrict__ w,
                                                       const float* __restrict__ bias,
                                                       hfu* __restrict__ y1) {
  __shared__ uint4 sm[2048];
  uint4* sA = sm;
  uint4* sB = sm + 1024;
  const int tid = threadIdx.x;
  const int lane = tid & 63, wid = tid >> 6;
  const int wm = wid >> 1, wn = wid & 1;
  const int lr = lane & 15, lq = lane >> 4;
  const int t0 = blockIdx.x * 128;
  const int r0 = blockIdx.y * 128;
  const int b = blockIdx.z;
  f32x4 acc[4][4] = {};
  for (int kt = 0; kt < 4; ++kt) {  // K=256
#pragma unroll
    for (int c = 0; c < 4; ++c) {
      const int cb = c * 256 + wid * 64;
      const int ch = cb + lane;
      const int ksub = ch >> 7, mn = ch & 127;
      const int k0 = kt * 64 + ksub * 8;
      GLOAD16(w + (size_t)(r0 + mn) * SKP + k0, &sA[cb]);
      int row = t0 + mn;
      if (row > T_LEN - 1) row = T_LEN - 1;
      if (PRE) {
        uint4 u = *(const uint4*)&skiph[((size_t)b * T_LEN + row) * SKP + k0];
        const _Float16* hp = (const _Float16*)&u;
        float v[8];
#pragma unroll
        for (int jj = 0; jj < 8; ++jj) v[jj] = fmaxf((float)hp[jj], 0.f);
        sB[ch] = pk8(v);
      } else {
        const float* src = skip + ((size_t)b * T_LEN + row) * SKP + k0;
        float4 f0 = *(const float4*)&src[0];
        float4 f1 = *(const float4*)&src[4];
        float v[8] = {fmaxf(f0.x, 0.f), fmaxf(f0.y, 0.f), fmaxf(f0.z, 0.f), fmaxf(f0.w, 0.f),
                      fmaxf(f1.x, 0.f), fmaxf(f1.y, 0.f), fmaxf(f1.z, 0.f), fmaxf(f1.w, 0.f)};
        sB[ch] = pk8(v);
      }
    }
    __syncthreads();
#pragma unroll
    for (int ks = 0; ks < 2; ++ks) {
      const int kb = (ks * 4 + lq) * 128;
      half8 av[4], bv[4];
#pragma unroll
      for (int r = 0; r < 4; ++r) {
        av[r] = *(const half8*)&sA[kb + wm * 64 + r * 16 + lr];
        bv[r] = *(const half8*)&sB[kb + wn * 64 + r * 16 + lr];
      }
#pragma unroll
      for (int mr = 0; mr < 4; ++mr)
#pragma unroll
        for (int nr = 0; nr < 4; ++nr)
          acc[mr][nr] = __builtin_amdgcn_mfma_f32_16x16x32_f16(av[mr], bv[nr], acc[mr][nr], 0, 0, 0);
    }
    __syncthreads();
  }
#pragma unroll
  for (int mr = 0; mr < 4; ++mr) {
    const int ob = r0 + wm * 64 + mr * 16 + lq * 4;
    float4 bb = *(const float4*)&bias[ob];
    const float bs[4] = {bb.x, bb.y, bb.z, bb.w};
#pragma unroll
    for (int nr = 0; nr < 4; ++nr) {
      const int t = t0 + wn * 64 + nr * 16 + lr;
      float v[4];
#pragma unroll
      for (int jj = 0; jj < 4; ++jj) v[jj] = fmaxf(acc[mr][nr][jj] + bs[jj], 0.f);
      *(uint2*)&y1[((size_t)b * HROWS + t) * SKP + ob] = make_uint2(pk2(v[0], v[1]), pk2(v[2], v[3]));
    }
  }
}

// ---------------- post2: out = W2 @ y1 + b2 -> d_out [b][t][q] fp32 ----------------
__global__ __launch_bounds__(256, 2) void post2_kernel(const hfu* __restrict__ y1,
                                                       const hfu* __restrict__ w,
                                                       const float* __restrict__ bias,
                                                       float* __restrict__ outp) {
  __shared__ uint4 sm[2048];
  uint4* sA = sm;
  uint4* sB = sm + 1024;
  const int tid = threadIdx.x;
  const int lane = tid & 63, wid = tid >> 6;
  const int wm = wid >> 1, wn = wid & 1;
  const int lr = lane & 15, lq = lane >> 4;
  const int t0 = blockIdx.x * 128;
  const int r0 = blockIdx.y * 128;
  const int b = blockIdx.z;
  f32x4 acc[4][4] = {};
  for (int kt = 0; kt < 4; ++kt) {
#pragma unroll
    for (int c = 0; c < 4; ++c) {
      const int cb = c * 256 + wid * 64;
      const int ch = cb + lane;
      const int ksub = ch >> 7, mn = ch & 127;
      const int k0 = kt * 64 + ksub * 8;
      GLOAD16(w + (size_t)(r0 + mn) * SKP + k0, &sA[cb]);
      GLOAD16(y1 + ((size_t)b * HROWS + t0 + mn) * SKP + k0, &sB[cb]);
    }
    __syncthreads();
#pragma unroll
    for (int ks = 0; ks < 2; ++ks) {
      const int kb = (ks * 4 + lq) * 128;
      half8 av[4], bv[4];
#pragma unroll
      for (int r = 0; r < 4; ++r) {
        av[r] = *(const half8*)&sA[kb + wm * 64 + r * 16 + lr];
        bv[r] = *(const half8*)&sB[kb + wn * 64 + r * 16 + lr];
      }
#pragma unroll
      for (int mr = 0; mr < 4; ++mr)
#pragma unroll
        for (int nr = 0; nr < 4; ++nr)
          acc[mr][nr] = __builtin_amdgcn_mfma_f32_16x16x32_f16(av[mr], bv[nr], acc[mr][nr], 0, 0, 0);
    }
    __syncthreads();
  }
#pragma unroll
  for (int mr = 0; mr < 4; ++mr) {
    const int ob = r0 + wm * 64 + mr * 16 + lq * 4;
    float4 bb = *(const float4*)&bias[ob];
#pragma unroll
    for (int nr = 0; nr < 4; ++nr) {
      const int t = t0 + wn * 64 + nr * 16 + lr;
      if (t < T_LEN) {
        float4 v;
        v.x = acc[mr][nr][0] + bb.x;
        v.y = acc[mr][nr][1] + bb.y;
        v.z = acc[mr][nr][2] + bb.z;
        v.w = acc[mr][nr][3] + bb.w;
        *(float4*)&outp[((size_t)b * T_LEN + t) * NQ + ob] = v;
      }
    }
  }
}

extern "C" void kernel_launch(void* const* d_in, const int* in_sizes, int n_in,
                              void* d_out, int out_size, void* d_ws, size_t ws_size,
                              hipStream_t stream) {
  const int* x = (const int*)d_in[0];
  const float* h = (const float*)d_in[1];
  const float* causal_w = (const float*)d_in[2];
  const float* causal_b = (const float*)d_in[3];
  const float* dil_sig_w = (const float*)d_in[4];
  const float* dil_sig_b = (const float*)d_in[5];
  const float* dil_tanh_w = (const float*)d_in[6];
  const float* dil_tanh_b = (const float*)d_in[7];
  const float* aux_sig_w = (const float*)d_in[8];
  const float* aux_sig_b = (const float*)d_in[9];
  const float* aux_tanh_w = (const float*)d_in[10];
  const float* aux_tanh_b = (const float*)d_in[11];
  const float* skip_w = (const float*)d_in[12];
  const float* skip_b = (const float*)d_in[13];
  const float* res_w = (const float*)d_in[14];
  const float* res_b = (const float*)d_in[15];
  const float* post1_w = (const float*)d_in[16];
  const float* post1_b = (const float*)d_in[17];
  const float* post2_w = (const float*)d_in[18];
  const float* post2_b = (const float*)d_in[19];
  float* outp = (float*)d_out;

  hipFuncSetAttribute((const void*)gate_kernel<1>,
                      hipFuncAttributeMaxDynamicSharedMemorySize, 131072);
  hipFuncSetAttribute((const void*)gate_kernel<0>,
                      hipFuncAttributeMaxDynamicSharedMemorySize, 131072);

  char* p = (char*)d_ws;
  auto alloc = [&](size_t bytes) {
    char* r = p;
    p += (bytes + 255) & ~(size_t)255;
    return r;
  };
  float* outf = (float*)alloc((size_t)BATCH * ROWS * CCH * 4);   // fp32 residual (PRE=0)
  float* skip = (float*)alloc((size_t)BATCH * T_LEN * SKP * 4);  // fp32 skip (PRE=0)
  hfu* zb = (hfu*)alloc((size_t)BATCH * HROWS * CCH * 2);        // z fp16 (reused as y1)
  hfu* hbf = (hfu*)alloc((size_t)BATCH * HROWS * AUXP * 2);
  hfu* auxsb = (hfu*)alloc((size_t)NLAYER * CCH * AUXP * 2);
  hfu* auxtb = (hfu*)alloc((size_t)NLAYER * CCH * AUXP * 2);
  hfu* p1b = (hfu*)alloc((size_t)NQ * SKP * 2);
  hfu* p2b = (hfu*)alloc((size_t)NQ * SKP * 2);
  float* cwt = (float*)alloc((size_t)2 * NQ * CCH * 4);          // transposed causal_w
  hfu* skiph = (hfu*)alloc((size_t)BATCH * T_LEN * SKP * 2);     // fp16 skip (PRE)
  hfu* y1 = zb;
  // optional (PRE) region
  hfu* outb = (hfu*)alloc((size_t)BATCH * ROWS * CCH * 2);       // fp16 residual (PRE)
  hfu* dilS = (hfu*)alloc((size_t)NLAYER * 2 * CCH * CCH * 2);
  hfu* dilT = (hfu*)alloc((size_t)NLAYER * 2 * CCH * CCH * 2);
  hfu* wsr = (hfu*)alloc((size_t)NLAYER * 768 * CCH * 2);
  const bool pre = ((size_t)(p - (char*)d_ws) <= ws_size);

  // weight conversions
  cvt_aux<<<256, 256, 0, stream>>>(aux_sig_w, auxsb);
  cvt_aux<<<256, 256, 0, stream>>>(aux_tanh_w, auxtb);
  cvt_copy<<<64, 256, 0, stream>>>(post1_w, p1b, NQ * SKP);
  cvt_copy<<<64, 256, 0, stream>>>(post2_w, p2b, NQ * SKP);
  cvt_cwt<<<1024, 256, 0, stream>>>(causal_w, cwt);
  if (pre) {
    cvt_dil2b<<<2048, 256, 0, stream>>>(dil_sig_w, dil_tanh_w, dilS, dilT);
    cvt_skipres<<<2048, 256, 0, stream>>>(skip_w, res_w, wsr);
  }

  // zero: skip + padded rows of the residual master in use
  if (pre) {
    zero16<<<512, 256, 0, stream>>>((uint4*)skiph, (int)((size_t)BATCH * T_LEN * SKP * 2 / 16));
    for (int b = 0; b < BATCH; ++b) {
      zero16<<<32, 256, 0, stream>>>((uint4*)(outb + (size_t)b * ROWS * CCH), PADF * CCH * 2 / 16);
      zero16<<<48, 256, 0, stream>>>((uint4*)(outb + ((size_t)b * ROWS + PADF + T_LEN) * CCH),
                                     (TPAD - T_LEN) * CCH * 2 / 16);
    }
  } else {
    zero16<<<512, 256, 0, stream>>>((uint4*)skip, (int)((size_t)BATCH * T_LEN * SKP * 4 / 16));
    for (int b = 0; b < BATCH; ++b) {
      zero16<<<64, 256, 0, stream>>>((uint4*)(outf + (size_t)b * ROWS * CCH), PADF * CCH * 4 / 16);
      zero16<<<96, 256, 0, stream>>>((uint4*)(outf + ((size_t)b * ROWS + PADF + T_LEN) * CCH),
                                     (TPAD - T_LEN) * CCH * 4 / 16);
    }
  }

  htrans_kernel<<<dim3(128, 2), 256, 0, stream>>>(h, hbf);
  if (pre)
    embed_kernel<1><<<dim3(2000, 2), 256, 0, stream>>>(x, cwt, causal_b, nullptr, outb);
  else
    embed_kernel<0><<<dim3(2000, 2), 256, 0, stream>>>(x, cwt, causal_b, outf, nullptr);

  for (int l = 0; l < NLAYER; ++l) {
    const int d = 1 << (l % 10);
    if (pre) {
      gate_kernel<1><<<256, 512, 131072, stream>>>(
          outb, nullptr, hbf, dilS + (size_t)l * 2 * CCH * CCH, dilT + (size_t)l * 2 * CCH * CCH,
          auxsb + (size_t)l * CCH * AUXP, auxtb + (size_t)l * CCH * AUXP,
          dil_sig_b + (size_t)l * CCH, aux_sig_b + (size_t)l * CCH,
          dil_tanh_b + (size_t)l * CCH, aux_tanh_b + (size_t)l * CCH, zb, d);
      update_kernel<1><<<768, 512, 0, stream>>>(
          zb, wsr + (size_t)l * 768 * CCH, nullptr, nullptr,
          skip_b + (size_t)l * SKP, res_b + (size_t)l * CCH, nullptr, skiph, nullptr, outb);
    } else {
      gate_kernel<0><<<256, 512, 131072, stream>>>(
          nullptr, outf, hbf, dil_sig_w + (size_t)l * CCH * CCH * 2,
          dil_tanh_w + (size_t)l * CCH * CCH * 2,
          auxsb + (size_t)l * CCH * AUXP, auxtb + (size_t)l * CCH * AUXP,
          dil_sig_b + (size_t)l * CCH, aux_sig_b + (size_t)l * CCH,
          dil_tanh_b + (size_t)l * CCH, aux_tanh_b + (size_t)l * CCH, zb, d);
      update_kernel<0><<<768, 512, 0, stream>>>(
          zb, nullptr, skip_w + (size_t)l * SKP * CCH, res_w + (size_t)l * CCH * CCH,
          skip_b + (size_t)l * SKP, res_b + (size_t)l * CCH, skip, nullptr, outf, nullptr);
    }
  }

  if (pre)
    post1_kernel<1><<<dim3(63, 2, BATCH), 256, 0, stream>>>(nullptr, skiph, p1b, post1_b, y1);
  else
    post1_kernel<0><<<dim3(63, 2, BATCH), 256, 0, stream>>>(skip, nullptr, p1b, post1_b, y1);
  post2_kernel<<<dim3(63, 2, BATCH), 256, 0, stream>>>(y1, p2b, post2_b, outp);
}